// Round 1
// baseline (751.271 us; speedup 1.0000x reference)
//
#include <hip/hip_runtime.h>
#include <stdint.h>

// ---------------------------------------------------------------------------
// MultiHeadedAttention (4-scale patch attention) for MI355X / gfx950
// Pipeline:
//   1. prep: Wq/Wk/Wv -> bf16 [768][256]; Wo -> bf16 [9][o][c]; mask scalars
//   2. x_t: x fp32 [t][c][p] -> bf16 [t][p][c]   (transpose+convert)
//   3. qkv GEMM (MFMA bf16): qkv_nat [t][768][p] bf16
//   4. mask gram G=M.M^T, rowsums r (fp32, tiny)
//   5. scores GEMM per scale (K-split + atomicAdd fp32)
//   6. logits = S*(a*G+b*rn+g*rm+d*S)/D  -> softmax -> P bf16 (padded)
//   7. PV GEMM per scale -> y_nat bf16 [t][256][p]  (stored in d_out low half)
//   8. y_t transpose -> [t][p][c] bf16 (reuses x_t space)
//   9. conv3x3 implicit GEMM (9 shifted 1x1) + bias + LeakyReLU -> d_out fp32
// Workspace layout (bytes):         ~272.9 MB total
//   qkv_nat   @ 0            (201326592)
//   x_t/y_t   @ 201326592    (67108864)
//   Wqkv_bf   @ 268435456    (393216)
//   Wo_bf     @ 268828672    (1179648)
//   bias_cat  @ 270008320    (3072)
//   msc       @ 270011392    (64)
//   scores    @ 270011456    (1118464)
//   G         @ 271129920    (1118464)
//   r         @ 272248384    (2720)
//   p_bf      @ 272251104    (560128)
// ---------------------------------------------------------------------------

typedef __attribute__((ext_vector_type(8))) short short8;
typedef __attribute__((ext_vector_type(4))) float floatx4;
typedef __attribute__((ext_vector_type(4))) unsigned int uintx4;

#define DEV static __device__ __forceinline__

DEV unsigned short f2bf(float f) {
  unsigned u = __builtin_bit_cast(unsigned, f);
  unsigned r = u + 0x7FFFu + ((u >> 16) & 1u);
  return (unsigned short)(r >> 16);
}

// scale sc in 0..3:  W=H=128>>sc, logW=7-sc, S=1<<(14-2sc), N=8<<(2sc),
// OHOW=4<<(2sc), OW=2<<sc, D=1<<(20-2sc)
DEV void patch_row(int n, int sc, int lw, int& pt, int& sp0) {
  pt = n >> (2 + 2 * sc);
  int rem = n & ((4 << (2 * sc)) - 1);
  int oh = rem >> (1 + sc), ow = rem & ((2 << sc) - 1);
  sp0 = (oh << (lw + 8)) + (ow << lw);
}

// ---------------- prep kernels ----------------
__global__ void k_prep_w(const float* __restrict__ Wq, const float* __restrict__ Wk,
                         const float* __restrict__ Wv, const float* __restrict__ bq,
                         const float* __restrict__ bk, const float* __restrict__ bv,
                         const float* __restrict__ Wmq, const float* __restrict__ bmq,
                         const float* __restrict__ Wmk, const float* __restrict__ bmk,
                         unsigned short* __restrict__ wqkv, float* __restrict__ bias,
                         float* __restrict__ msc) {
  int b = blockIdx.x;
  int t = threadIdx.x;
  if (b < 768) {
    const float* src = b < 256 ? (Wq + b * 256) : (b < 512 ? (Wk + (b - 256) * 256)
                                                           : (Wv + (b - 512) * 256));
    wqkv[b * 256 + t] = f2bf(src[t]);
    if (t == 0) bias[b] = b < 256 ? bq[b] : (b < 512 ? bk[b - 256] : bv[b - 512]);
  } else {
    int sc = t >> 6, lane = t & 63;
    int ch = sc * 64 + lane;
    float a0 = Wmq[ch] * Wmk[ch];
    float a1 = Wmq[ch] * bmk[ch];
    float a2 = bmq[ch] * Wmk[ch];
    float a3 = bmq[ch] * bmk[ch];
    for (int off = 32; off; off >>= 1) {
      a0 += __shfl_xor(a0, off); a1 += __shfl_xor(a1, off);
      a2 += __shfl_xor(a2, off); a3 += __shfl_xor(a3, off);
    }
    if (lane == 0) {
      msc[sc * 4 + 0] = a0; msc[sc * 4 + 1] = a1;
      msc[sc * 4 + 2] = a2; msc[sc * 4 + 3] = a3;
    }
  }
}

__global__ void k_prep_wo(const float* __restrict__ Wo, unsigned short* __restrict__ wobf) {
  int blk = blockIdx.x;
  int didx = blk >> 8, o = blk & 255, c = threadIdx.x;
  wobf[didx * 65536 + o * 256 + c] = f2bf(Wo[o * 2304 + c * 9 + didx]);
}

__global__ void k_zero(float* __restrict__ scores, unsigned int* __restrict__ pbuf) {
  int i = blockIdx.x * 256 + threadIdx.x;
  if (i < 279616) scores[i] = 0.f;
  if (i < 140032) pbuf[i] = 0u;
}

// ---------------- transpose kernels ----------------
__global__ __launch_bounds__(256) void k_xt(const float* __restrict__ x,
                                            unsigned short* __restrict__ xt) {
  __shared__ __align__(16) unsigned short tile[64][72];
  int p0 = blockIdx.x * 64, c0 = blockIdx.y * 64, t = blockIdx.z;
  int tid = threadIdx.x;
  {
    int cc = tid >> 2, pq = (tid & 3) * 16;
    const float* src = x + ((t * 256 + c0 + cc) * 65536 + p0 + pq);
    __align__(16) unsigned short tmp[16];
#pragma unroll
    for (int e = 0; e < 16; e += 4) {
      floatx4 v = *(const floatx4*)(src + e);
      tmp[e + 0] = f2bf(v[0]); tmp[e + 1] = f2bf(v[1]);
      tmp[e + 2] = f2bf(v[2]); tmp[e + 3] = f2bf(v[3]);
    }
    *(uintx4*)&tile[cc][pq] = *(const uintx4*)&tmp[0];
    *(uintx4*)&tile[cc][pq + 8] = *(const uintx4*)&tmp[8];
  }
  __syncthreads();
  {
    int pp = tid >> 2, cg = (tid & 3) * 16;
    __align__(16) unsigned short outv[16];
#pragma unroll
    for (int e = 0; e < 16; ++e) outv[e] = tile[cg + e][pp];
    unsigned short* dst = xt + ((t * 65536 + p0 + pp) * 256 + c0 + cg);
    *(uintx4*)dst = *(const uintx4*)&outv[0];
    *(uintx4*)(dst + 8) = *(const uintx4*)&outv[8];
  }
}

__global__ __launch_bounds__(256) void k_yt(const unsigned short* __restrict__ ynat,
                                            unsigned short* __restrict__ yt) {
  __shared__ __align__(16) unsigned short tile[64][72];
  int p0 = blockIdx.x * 64, c0 = blockIdx.y * 64, t = blockIdx.z;
  int tid = threadIdx.x;
  {
    int cc = tid >> 2, pq = (tid & 3) * 16;
    const unsigned short* src = ynat + ((t * 256 + c0 + cc) * 65536 + p0 + pq);
    *(uintx4*)&tile[cc][pq] = *(const uintx4*)src;
    *(uintx4*)&tile[cc][pq + 8] = *(const uintx4*)(src + 8);
  }
  __syncthreads();
  {
    int pp = tid >> 2, cg = (tid & 3) * 16;
    __align__(16) unsigned short outv[16];
#pragma unroll
    for (int e = 0; e < 16; ++e) outv[e] = tile[cg + e][pp];
    unsigned short* dst = yt + ((t * 65536 + p0 + pp) * 256 + c0 + cg);
    *(uintx4*)dst = *(const uintx4*)&outv[0];
    *(uintx4*)(dst + 8) = *(const uintx4*)&outv[8];
  }
}

// ---------------- QKV GEMM: C[c][p2] = Wqkv[c][:] . x_t[p2][:] + bias ----------------
__global__ __launch_bounds__(256) void k_qkv(const unsigned short* __restrict__ xt,
                                             const unsigned short* __restrict__ wqkv,
                                             const float* __restrict__ bias,
                                             unsigned short* __restrict__ qkv) {
  __shared__ __align__(16) unsigned short As[128][40];
  __shared__ __align__(16) unsigned short Bs[128][40];
  int n0 = blockIdx.x * 128;  // p2
  int m0 = blockIdx.y * 128;  // c
  int tid = threadIdx.x;
  int w = tid >> 6, l = tid & 63;
  int wr = w >> 1, wc = w & 1;
  int srow = tid >> 1, kh = (tid & 1) * 16;
  floatx4 zf = {0.f, 0.f, 0.f, 0.f};
  floatx4 acc[4][4];
#pragma unroll
  for (int i = 0; i < 4; ++i)
#pragma unroll
    for (int j = 0; j < 4; ++j) acc[i][j] = zf;

  for (int ks = 0; ks < 8; ++ks) {
    int k0 = ks * 32;
    const unsigned short* ga = wqkv + (m0 + srow) * 256 + k0 + kh;
    const unsigned short* gb = xt + (n0 + srow) * 256 + k0 + kh;
    uintx4 a0 = *(const uintx4*)ga, a1 = *(const uintx4*)(ga + 8);
    uintx4 b0 = *(const uintx4*)gb, b1 = *(const uintx4*)(gb + 8);
    __syncthreads();
    *(uintx4*)&As[srow][kh] = a0; *(uintx4*)&As[srow][kh + 8] = a1;
    *(uintx4*)&Bs[srow][kh] = b0; *(uintx4*)&Bs[srow][kh + 8] = b1;
    __syncthreads();
    int koff = (l >> 4) * 8;
    short8 af[4], bfr[4];
#pragma unroll
    for (int f = 0; f < 4; ++f) {
      af[f] = *(const short8*)&As[wr * 64 + f * 16 + (l & 15)][koff];
      bfr[f] = *(const short8*)&Bs[wc * 64 + f * 16 + (l & 15)][koff];
    }
#pragma unroll
    for (int fm = 0; fm < 4; ++fm)
#pragma unroll
      for (int fn = 0; fn < 4; ++fn)
        acc[fm][fn] = __builtin_amdgcn_mfma_f32_16x16x32_bf16(af[fm], bfr[fn], acc[fm][fn], 0, 0, 0);
  }
#pragma unroll
  for (int fm = 0; fm < 4; ++fm) {
    int crow = m0 + wr * 64 + fm * 16 + (l >> 4) * 4;
#pragma unroll
    for (int rr = 0; rr < 4; ++rr) {
      float bv = bias[crow + rr];
#pragma unroll
      for (int fn = 0; fn < 4; ++fn) {
        int pcol = n0 + wc * 64 + fn * 16 + (l & 15);
        int t = pcol >> 16, p = pcol & 65535;
        qkv[(t * 768 + crow + rr) * 65536 + p] = f2bf(acc[fm][fn][rr] + bv);
      }
    }
  }
}

// ---------------- mask gram / rowsum ----------------
__global__ void k_gram(const float* __restrict__ m, float* __restrict__ G) {
  int gw = blockIdx.x * 4 + (threadIdx.x >> 6);
  int lane = threadIdx.x & 63;
  int sc, pair, soff;
  if (gw < 64)         { sc = 0; pair = gw;          soff = 0; }
  else if (gw < 1088)  { sc = 1; pair = gw - 64;     soff = 64; }
  else if (gw < 17472) { sc = 2; pair = gw - 1088;   soff = 1088; }
  else                 { sc = 3; pair = gw - 17472;  soff = 17472; }
  int lw = 7 - sc, W = 1 << lw;
  int N = 8 << (2 * sc);
  int n = pair >> (3 + 2 * sc);
  int mm = pair & (N - 1);
  int ptn, spn, ptm, spm;
  patch_row(n, sc, lw, ptn, spn);
  patch_row(mm, sc, lw, ptm, spm);
  int bn = ptn * 65536 + spn, bm = ptm * 65536 + spm;
  int S = 1 << (14 - 2 * sc);
  float acc = 0.f;
  for (int s = lane; s < S; s += 64) {
    int hh = s >> lw, ww = s & (W - 1);
    int o = (hh << 8) + ww;
    acc += m[bn + o] * m[bm + o];
  }
  for (int off = 32; off; off >>= 1) acc += __shfl_xor(acc, off);
  if (lane == 0) G[soff + pair] = acc;
}

__global__ void k_rsum(const float* __restrict__ m, float* __restrict__ rbuf) {
  int row = blockIdx.x, lane = threadIdx.x;
  int sc, n;
  if (row < 8)        { sc = 0; n = row; }
  else if (row < 40)  { sc = 1; n = row - 8; }
  else if (row < 168) { sc = 2; n = row - 40; }
  else                { sc = 3; n = row - 168; }
  int lw = 7 - sc, W = 1 << lw;
  int pt, sp0;
  patch_row(n, sc, lw, pt, sp0);
  int base = pt * 65536 + sp0;
  int S = 1 << (14 - 2 * sc);
  float acc = 0.f;
  for (int s = lane; s < S; s += 64) {
    int hh = s >> lw, ww = s & (W - 1);
    acc += m[base + (hh << 8) + ww];
  }
  for (int off = 32; off; off >>= 1) acc += __shfl_xor(acc, off);
  if (lane == 0) rbuf[row] = acc;
}

// ---------------- scores GEMM (K-split, atomic accumulate) ----------------
__global__ __launch_bounds__(256) void k_scores(const unsigned short* __restrict__ qkv,
                                                float* __restrict__ scores,
                                                int sc, int soff, int ksteps) {
  int lw = 7 - sc, W = 1 << lw;
  int lS = 14 - 2 * sc;
  int N = 8 << (2 * sc);
  int n0 = blockIdx.x * 32, m0 = blockIdx.y * 32;
  int kbase = blockIdx.z * (ksteps * 32);
  __shared__ __align__(16) unsigned short As[32][40];
  __shared__ __align__(16) unsigned short Bs[32][40];
  int tid = threadIdx.x;
  int w = tid >> 6, l = tid & 63;
  int wr = w >> 1, wc = w & 1;
  floatx4 acc = {0.f, 0.f, 0.f, 0.f};
  bool isA = tid < 128;
  int u = tid & 127;
  int srow = u >> 2, kg = (u & 3) * 8;
  int grow = (isA ? n0 : m0) + srow;
  int cb = (isA ? 0 : 256) + sc * 64;
  int pt = 0, sp0 = 0;
  bool valid = grow < N;
  if (valid) patch_row(grow, sc, lw, pt, sp0);
  uintx4 zu = {0u, 0u, 0u, 0u};

  for (int ks = 0; ks < ksteps; ++ks) {
    int k0 = kbase + ks * 32 + kg;
    uintx4 v = zu;
    if (valid) {
      int cl = k0 >> lS;
      int s = k0 & ((1 << lS) - 1);
      int hh = s >> lw, ww = s & (W - 1);
      int addr = (pt * 768 + cb + cl) * 65536 + sp0 + (hh << 8) + ww;
      v = *(const uintx4*)(qkv + addr);
    }
    __syncthreads();
    if (isA) *(uintx4*)&As[srow][kg] = v;
    else     *(uintx4*)&Bs[srow][kg] = v;
    __syncthreads();
    int koff = (l >> 4) * 8;
    short8 a = *(const short8*)&As[wr * 16 + (l & 15)][koff];
    short8 b = *(const short8*)&Bs[wc * 16 + (l & 15)][koff];
    acc = __builtin_amdgcn_mfma_f32_16x16x32_bf16(a, b, acc, 0, 0, 0);
  }
  int rrow = n0 + wr * 16 + (l >> 4) * 4;
  int ccol = m0 + wc * 16 + (l & 15);
  if (ccol < N) {
#pragma unroll
    for (int rr = 0; rr < 4; ++rr)
      if (rrow + rr < N) atomicAdd(&scores[soff + (rrow + rr) * N + ccol], acc[rr]);
  }
}

// ---------------- logits + softmax -> P bf16 ----------------
__global__ void k_softmax(const float* __restrict__ scores, const float* __restrict__ G,
                          const float* __restrict__ rbuf, const float* __restrict__ msc,
                          unsigned short* __restrict__ pbuf) {
  int row = blockIdx.x, lane = threadIdx.x;
  int sc, n, roff, soff, poff;
  if (row < 8)        { sc = 0; n = row;       roff = 0;   soff = 0;     poff = 0; }
  else if (row < 40)  { sc = 1; n = row - 8;   roff = 8;   soff = 64;    poff = 512; }
  else if (row < 168) { sc = 2; n = row - 40;  roff = 40;  soff = 1088;  poff = 1536; }
  else                { sc = 3; n = row - 168; roff = 168; soff = 17472; poff = 17920; }
  int N = 8 << (2 * sc);
  int Kpad = (sc < 2) ? 32 : N;
  float Sf = (float)(1 << (14 - 2 * sc));
  float invD = 1.0f / (float)(1 << (20 - 2 * sc));
  float alpha = msc[sc * 4 + 0], beta = msc[sc * 4 + 1];
  float gamma = msc[sc * 4 + 2], delta = msc[sc * 4 + 3];
  float rn = rbuf[roff + n];
  float vals[8];
  float mx = -1e30f;
#pragma unroll
  for (int j = 0; j < 8; ++j) {
    float v = -1e30f;
    int mcol = lane + j * 64;
    if (j * 64 < N && mcol < N) {
      float sq = scores[soff + n * N + mcol];
      float g = G[soff + n * N + mcol];
      float rm = rbuf[roff + mcol];
      v = sq * (alpha * g + beta * rn + gamma * rm + delta * Sf) * invD;
    }
    vals[j] = v;
    mx = fmaxf(mx, v);
  }
  for (int off = 32; off; off >>= 1) mx = fmaxf(mx, __shfl_xor(mx, off));
  float sum = 0.f;
#pragma unroll
  for (int j = 0; j < 8; ++j) {
    int mcol = lane + j * 64;
    float e = 0.f;
    if (j * 64 < N && mcol < N) e = __expf(vals[j] - mx);
    vals[j] = e;
    sum += e;
  }
  for (int off = 32; off; off >>= 1) sum += __shfl_xor(sum, off);
  float inv = 1.f / sum;
#pragma unroll
  for (int j = 0; j < 8; ++j) {
    int mcol = lane + j * 64;
    if (j * 64 < N && mcol < N) pbuf[poff + n * Kpad + mcol] = f2bf(vals[j] * inv);
  }
}

// ---------------- PV GEMM: y[n][d] = sum_m P[n][m] V[m][d] -> y_nat ----------------
__global__ __launch_bounds__(256) void k_pv(const unsigned short* __restrict__ qkv,
                                            const unsigned short* __restrict__ pbuf,
                                            unsigned short* __restrict__ ynat,
                                            int sc, int WR, int logWC, int poff) {
  int lw = 7 - sc, W = 1 << lw;
  int lS = 14 - 2 * sc;
  int N = 8 << (2 * sc);
  int Kpad = (sc < 2) ? 32 : N;
  int WC = 1 << logWC;
  int d0 = blockIdx.x * (WC * 64);
  int nb = blockIdx.y * (WR * 16);
  __shared__ __align__(16) unsigned short As[64][40];
  __shared__ __align__(16) unsigned short Bt[256][40];
  int tid = threadIdx.x;
  int w = tid >> 6, l = tid & 63;
  int wr = w >> logWC, wc = w & (WC - 1);
  floatx4 zf = {0.f, 0.f, 0.f, 0.f};
  floatx4 acc[4];
#pragma unroll
  for (int i = 0; i < 4; ++i) acc[i] = zf;
  int bm = tid & 31, dgrp = tid >> 5;
  bool doA = tid < WR * 64;
  int arow = tid >> 2, akg = (tid & 3) * 8;
  int ksteps = Kpad >> 5;
  uintx4 zu = {0u, 0u, 0u, 0u};

  for (int ks = 0; ks < ksteps; ++ks) {
    int k0 = ks * 32;
    uintx4 av = zu;
    if (doA) av = *(const uintx4*)(pbuf + poff + (nb + arow) * Kpad + k0 + akg);
    int gm = k0 + bm;
    bool mvalid = gm < N;
    int pt = 0, sp0 = 0;
    if (mvalid) patch_row(gm, sc, lw, pt, sp0);
    uintx4 bv[4];
#pragma unroll
    for (int uu = 0; uu < 4; ++uu) {
      bv[uu] = zu;
      if (uu < WC && mvalid) {
        int d = d0 + (dgrp * WC + uu) * 8;
        int cl = d >> lS;
        int s = d & ((1 << lS) - 1);
        int hh = s >> lw, ww = s & (W - 1);
        int addr = (pt * 768 + 512 + sc * 64 + cl) * 65536 + sp0 + (hh << 8) + ww;
        bv[uu] = *(const uintx4*)(qkv + addr);
      }
    }
    __syncthreads();
    if (doA) *(uintx4*)&As[arow][akg] = av;
#pragma unroll
    for (int uu = 0; uu < 4; ++uu) {
      if (uu < WC) {
        int dl = (dgrp * WC + uu) * 8;
        unsigned v0 = bv[uu][0], v1 = bv[uu][1], v2 = bv[uu][2], v3 = bv[uu][3];
        Bt[dl + 0][bm] = (unsigned short)v0; Bt[dl + 1][bm] = (unsigned short)(v0 >> 16);
        Bt[dl + 2][bm] = (unsigned short)v1; Bt[dl + 3][bm] = (unsigned short)(v1 >> 16);
        Bt[dl + 4][bm] = (unsigned short)v2; Bt[dl + 5][bm] = (unsigned short)(v2 >> 16);
        Bt[dl + 6][bm] = (unsigned short)v3; Bt[dl + 7][bm] = (unsigned short)(v3 >> 16);
      }
    }
    __syncthreads();
    int koff = (l >> 4) * 8;
    short8 a = *(const short8*)&As[wr * 16 + (l & 15)][koff];
#pragma unroll
    for (int fn = 0; fn < 4; ++fn) {
      short8 b = *(const short8*)&Bt[wc * 64 + fn * 16 + (l & 15)][koff];
      acc[fn] = __builtin_amdgcn_mfma_f32_16x16x32_bf16(a, b, acc[fn], 0, 0, 0);
    }
    __syncthreads();
  }
  int nrow = nb + wr * 16 + (l >> 4) * 4;
#pragma unroll
  for (int rr = 0; rr < 4; ++rr) {
    int n = nrow + rr;
    if (n < N) {
      int pt, sp0;
      patch_row(n, sc, lw, pt, sp0);
#pragma unroll
      for (int fn = 0; fn < 4; ++fn) {
        int d = d0 + wc * 64 + fn * 16 + (l & 15);
        int cl = d >> lS;
        int s = d & ((1 << lS) - 1);
        int hh = s >> lw, ww = s & (W - 1);
        int c = sc * 64 + cl;
        ynat[(pt * 256 + c) * 65536 + sp0 + (hh << 8) + ww] = f2bf(acc[fn][rr]);
      }
    }
  }
}

// ---------------- conv3x3 implicit GEMM + bias + LeakyReLU ----------------
__global__ __launch_bounds__(256) void k_conv(const unsigned short* __restrict__ yt,
                                              const unsigned short* __restrict__ wo,
                                              const float* __restrict__ bo,
                                              float* __restrict__ out) {
  __shared__ __align__(16) unsigned short As[128][40];
  __shared__ __align__(16) unsigned short Bs[128][40];
  int n0 = blockIdx.x * 128;  // p2
  int m0 = blockIdx.y * 128;  // o
  int tid = threadIdx.x;
  int w = tid >> 6, l = tid & 63;
  int wr = w >> 1, wc = w & 1;
  int srow = tid >> 1, kh = (tid & 1) * 16;
  int p2 = n0 + srow;
  int tt = p2 >> 16, yy = (p2 >> 8) & 255, xx = p2 & 255;
  floatx4 zf = {0.f, 0.f, 0.f, 0.f};
  floatx4 acc[4][4];
#pragma unroll
  for (int i = 0; i < 4; ++i)
#pragma unroll
    for (int j = 0; j < 4; ++j) acc[i][j] = zf;
  uintx4 zu = {0u, 0u, 0u, 0u};

#pragma unroll
  for (int didx = 0; didx < 9; ++didx) {
    const int dy = didx / 3 - 1, dx = didx % 3 - 1;
    int yq = yy + dy, xq = xx + dx;
    bool bvalid = ((unsigned)yq < 256u) && ((unsigned)xq < 256u);
    int boff = ((tt * 65536 + (yq << 8) + xq) << 8) + kh;
    int aoff = didx * 65536 + (m0 + srow) * 256 + kh;
#pragma unroll 1
    for (int c8 = 0; c8 < 8; ++c8) {
      int cch = c8 * 32;
      uintx4 b0 = zu, b1 = zu;
      if (bvalid) {
        b0 = *(const uintx4*)(yt + boff + cch);
        b1 = *(const uintx4*)(yt + boff + cch + 8);
      }
      uintx4 a0 = *(const uintx4*)(wo + aoff + cch);
      uintx4 a1 = *(const uintx4*)(wo + aoff + cch + 8);
      __syncthreads();
      *(uintx4*)&As[srow][kh] = a0; *(uintx4*)&As[srow][kh + 8] = a1;
      *(uintx4*)&Bs[srow][kh] = b0; *(uintx4*)&Bs[srow][kh + 8] = b1;
      __syncthreads();
      int koff = (l >> 4) * 8;
      short8 af[4], bfr[4];
#pragma unroll
      for (int f = 0; f < 4; ++f) {
        af[f] = *(const short8*)&As[wr * 64 + f * 16 + (l & 15)][koff];
        bfr[f] = *(const short8*)&Bs[wc * 64 + f * 16 + (l & 15)][koff];
      }
#pragma unroll
      for (int fm = 0; fm < 4; ++fm)
#pragma unroll
        for (int fn = 0; fn < 4; ++fn)
          acc[fm][fn] = __builtin_amdgcn_mfma_f32_16x16x32_bf16(af[fm], bfr[fn], acc[fm][fn], 0, 0, 0);
    }
  }
#pragma unroll
  for (int fm = 0; fm < 4; ++fm) {
    int o = m0 + wr * 64 + fm * 16 + (l >> 4) * 4;
#pragma unroll
    for (int rr = 0; rr < 4; ++rr) {
      float bias = bo[o + rr];
#pragma unroll
      for (int fn = 0; fn < 4; ++fn) {
        int p2o = n0 + wc * 64 + fn * 16 + (l & 15);
        int t = p2o >> 16, p = p2o & 65535;
        float z = acc[fm][fn][rr] + bias;
        out[(t * 256 + o + rr) * 65536 + p] = z > 0.f ? z : 0.2f * z;
      }
    }
  }
}

// ---------------------------------------------------------------------------
extern "C" void kernel_launch(void* const* d_in, const int* in_sizes, int n_in,
                              void* d_out, int out_size, void* d_ws, size_t ws_size,
                              hipStream_t stream) {
  const float* x   = (const float*)d_in[0];
  const float* m   = (const float*)d_in[1];
  const float* Wq  = (const float*)d_in[2];
  const float* bq  = (const float*)d_in[3];
  const float* Wk  = (const float*)d_in[4];
  const float* bk  = (const float*)d_in[5];
  const float* Wv  = (const float*)d_in[6];
  const float* bv  = (const float*)d_in[7];
  const float* Wmq = (const float*)d_in[8];
  const float* bmq = (const float*)d_in[9];
  const float* Wmk = (const float*)d_in[10];
  const float* bmk = (const float*)d_in[11];
  const float* Wo  = (const float*)d_in[12];
  const float* bo  = (const float*)d_in[13];

  char* ws = (char*)d_ws;
  unsigned short* qkv   = (unsigned short*)(ws);
  unsigned short* xt    = (unsigned short*)(ws + 201326592);
  unsigned short* wqkv  = (unsigned short*)(ws + 268435456);
  unsigned short* wobf  = (unsigned short*)(ws + 268828672);
  float* bias           = (float*)(ws + 270008320);
  float* msc            = (float*)(ws + 270011392);
  float* scores         = (float*)(ws + 270011456);
  float* G              = (float*)(ws + 271129920);
  float* rbuf           = (float*)(ws + 272248384);
  unsigned short* pbuf  = (unsigned short*)(ws + 272251104);
  float* out            = (float*)d_out;
  unsigned short* ynat  = (unsigned short*)d_out;  // low half of d_out as bf16 scratch
  unsigned short* yt    = xt;                      // reuse x_t space

  k_prep_w<<<dim3(769), dim3(256), 0, stream>>>(Wq, Wk, Wv, bq, bk, bv, Wmq, bmq, Wmk, bmk,
                                                wqkv, bias, msc);
  k_prep_wo<<<dim3(2304), dim3(256), 0, stream>>>(Wo, wobf);
  k_zero<<<dim3(1093), dim3(256), 0, stream>>>(scores, (unsigned int*)pbuf);
  k_xt<<<dim3(1024, 4, 2), dim3(256), 0, stream>>>(x, xt);
  k_qkv<<<dim3(1024, 6), dim3(256), 0, stream>>>(xt, wqkv, bias, qkv);
  k_gram<<<dim3(69904), dim3(256), 0, stream>>>(m, G);
  k_rsum<<<dim3(680), dim3(64), 0, stream>>>(m, rbuf);
  k_scores<<<dim3(1, 1, 1024), dim3(256), 0, stream>>>(qkv, scores, 0, 0, 32);
  k_scores<<<dim3(1, 1, 256), dim3(256), 0, stream>>>(qkv, scores, 1, 64, 32);
  k_scores<<<dim3(4, 4, 64), dim3(256), 0, stream>>>(qkv, scores, 2, 1088, 32);
  k_scores<<<dim3(16, 16, 4), dim3(256), 0, stream>>>(qkv, scores, 3, 17472, 128);
  k_softmax<<<dim3(680), dim3(64), 0, stream>>>(scores, G, rbuf, msc, pbuf);
  k_pv<<<dim3(4096, 1), dim3(256), 0, stream>>>(qkv, pbuf, ynat, 0, 1, 2, 0);
  k_pv<<<dim3(2048, 1), dim3(256), 0, stream>>>(qkv, pbuf, ynat, 1, 2, 1, 512);
  k_pv<<<dim3(1024, 2), dim3(256), 0, stream>>>(qkv, pbuf, ynat, 2, 4, 0, 1536);
  k_pv<<<dim3(256, 8), dim3(256), 0, stream>>>(qkv, pbuf, ynat, 3, 4, 0, 17920);
  k_yt<<<dim3(1024, 4, 2), dim3(256), 0, stream>>>(ynat, yt);
  k_conv<<<dim3(1024, 2), dim3(256), 0, stream>>>(yt, wobf, bo, out);
}

// Round 2
// 712.302 us; speedup vs baseline: 1.0547x; 1.0547x over previous
//
#include <hip/hip_runtime.h>
#include <stdint.h>

// ---------------------------------------------------------------------------
// MultiHeadedAttention (4-scale patch attention) for MI355X / gfx950
// R2: T2 XOR-swizzled LDS (conflict-free), K-chunk 64 + reg prefetch in
//     qkv/conv, T1 XCD-chunked block swizzle, PV transpose packed+swizzled.
// Workspace layout unchanged (~272.9 MB).
// ---------------------------------------------------------------------------

typedef __attribute__((ext_vector_type(8))) short short8;
typedef __attribute__((ext_vector_type(4))) float floatx4;
typedef __attribute__((ext_vector_type(4))) unsigned int uintx4;

#define DEV static __device__ __forceinline__

DEV unsigned short f2bf(float f) {
  unsigned u = __builtin_bit_cast(unsigned, f);
  unsigned r = u + 0x7FFFu + ((u >> 16) & 1u);
  return (unsigned short)(r >> 16);
}

DEV void patch_row(int n, int sc, int lw, int& pt, int& sp0) {
  pt = n >> (2 + 2 * sc);
  int rem = n & ((4 << (2 * sc)) - 1);
  int oh = rem >> (1 + sc), ow = rem & ((2 << sc) - 1);
  sp0 = (oh << (lw + 8)) + (ow << lw);
}

// ---------------- prep kernels ----------------
__global__ void k_prep_w(const float* __restrict__ Wq, const float* __restrict__ Wk,
                         const float* __restrict__ Wv, const float* __restrict__ bq,
                         const float* __restrict__ bk, const float* __restrict__ bv,
                         const float* __restrict__ Wmq, const float* __restrict__ bmq,
                         const float* __restrict__ Wmk, const float* __restrict__ bmk,
                         unsigned short* __restrict__ wqkv, float* __restrict__ bias,
                         float* __restrict__ msc) {
  int b = blockIdx.x;
  int t = threadIdx.x;
  if (b < 768) {
    const float* src = b < 256 ? (Wq + b * 256) : (b < 512 ? (Wk + (b - 256) * 256)
                                                           : (Wv + (b - 512) * 256));
    wqkv[b * 256 + t] = f2bf(src[t]);
    if (t == 0) bias[b] = b < 256 ? bq[b] : (b < 512 ? bk[b - 256] : bv[b - 512]);
  } else {
    int sc = t >> 6, lane = t & 63;
    int ch = sc * 64 + lane;
    float a0 = Wmq[ch] * Wmk[ch];
    float a1 = Wmq[ch] * bmk[ch];
    float a2 = bmq[ch] * Wmk[ch];
    float a3 = bmq[ch] * bmk[ch];
    for (int off = 32; off; off >>= 1) {
      a0 += __shfl_xor(a0, off); a1 += __shfl_xor(a1, off);
      a2 += __shfl_xor(a2, off); a3 += __shfl_xor(a3, off);
    }
    if (lane == 0) {
      msc[sc * 4 + 0] = a0; msc[sc * 4 + 1] = a1;
      msc[sc * 4 + 2] = a2; msc[sc * 4 + 3] = a3;
    }
  }
}

__global__ void k_prep_wo(const float* __restrict__ Wo, unsigned short* __restrict__ wobf) {
  int blk = blockIdx.x;
  int didx = blk >> 8, o = blk & 255, c = threadIdx.x;
  wobf[didx * 65536 + o * 256 + c] = f2bf(Wo[o * 2304 + c * 9 + didx]);
}

__global__ void k_zero(float* __restrict__ scores, unsigned int* __restrict__ pbuf) {
  int i = blockIdx.x * 256 + threadIdx.x;
  if (i < 279616) scores[i] = 0.f;
  if (i < 140032) pbuf[i] = 0u;
}

// ---------------- transpose kernels ----------------
__global__ __launch_bounds__(256) void k_xt(const float* __restrict__ x,
                                            unsigned short* __restrict__ xt) {
  __shared__ __align__(16) unsigned short tile[64][72];
  int p0 = blockIdx.x * 64, c0 = blockIdx.y * 64, t = blockIdx.z;
  int tid = threadIdx.x;
  {
    int cc = tid >> 2, pq = (tid & 3) * 16;
    const float* src = x + ((t * 256 + c0 + cc) * 65536 + p0 + pq);
    __align__(16) unsigned short tmp[16];
#pragma unroll
    for (int e = 0; e < 16; e += 4) {
      floatx4 v = *(const floatx4*)(src + e);
      tmp[e + 0] = f2bf(v[0]); tmp[e + 1] = f2bf(v[1]);
      tmp[e + 2] = f2bf(v[2]); tmp[e + 3] = f2bf(v[3]);
    }
    *(uintx4*)&tile[cc][pq] = *(const uintx4*)&tmp[0];
    *(uintx4*)&tile[cc][pq + 8] = *(const uintx4*)&tmp[8];
  }
  __syncthreads();
  {
    int pp = tid >> 2, cg = (tid & 3) * 16;
    __align__(16) unsigned short outv[16];
#pragma unroll
    for (int e = 0; e < 16; ++e) outv[e] = tile[cg + e][pp];
    unsigned short* dst = xt + ((t * 65536 + p0 + pp) * 256 + c0 + cg);
    *(uintx4*)dst = *(const uintx4*)&outv[0];
    *(uintx4*)(dst + 8) = *(const uintx4*)&outv[8];
  }
}

__global__ __launch_bounds__(256) void k_yt(const unsigned short* __restrict__ ynat,
                                            unsigned short* __restrict__ yt) {
  __shared__ __align__(16) unsigned short tile[64][72];
  int p0 = blockIdx.x * 64, c0 = blockIdx.y * 64, t = blockIdx.z;
  int tid = threadIdx.x;
  {
    int cc = tid >> 2, pq = (tid & 3) * 16;
    const unsigned short* src = ynat + ((t * 256 + c0 + cc) * 65536 + p0 + pq);
    *(uintx4*)&tile[cc][pq] = *(const uintx4*)src;
    *(uintx4*)&tile[cc][pq + 8] = *(const uintx4*)(src + 8);
  }
  __syncthreads();
  {
    int pp = tid >> 2, cg = (tid & 3) * 16;
    __align__(16) unsigned short outv[16];
#pragma unroll
    for (int e = 0; e < 16; ++e) outv[e] = tile[cg + e][pp];
    unsigned short* dst = yt + ((t * 65536 + p0 + pp) * 256 + c0 + cg);
    *(uintx4*)dst = *(const uintx4*)&outv[0];
    *(uintx4*)(dst + 8) = *(const uintx4*)&outv[8];
  }
}

// ---------------- QKV GEMM (swizzled LDS, K-chunk 64, prefetch) ----------------
__global__ __launch_bounds__(256) void k_qkv(const unsigned short* __restrict__ xt,
                                             const unsigned short* __restrict__ wqkv,
                                             const float* __restrict__ bias,
                                             unsigned short* __restrict__ qkv) {
  __shared__ __align__(16) unsigned short As[128][64];
  __shared__ __align__(16) unsigned short Bs[128][64];
  int flat = blockIdx.x + (blockIdx.y << 10);          // grid (1024, 6)
  int lg = ((flat & 7) * 768) + (flat >> 3);           // bijective XCD chunking
  int n_t = lg / 6, m_t = lg - n_t * 6;                // m-inner: B reuse on-XCD
  int n0 = n_t << 7, m0 = m_t << 7;
  int tid = threadIdx.x;
  int w = tid >> 6, l = tid & 63;
  int wr = w >> 1, wc = w & 1;
  int l15 = l & 15, lhi = l >> 4;
  int sr = tid >> 1, sbase = (tid & 1) * 4, r7 = sr & 7;
  const unsigned short* gA = wqkv + (m0 + sr) * 256 + sbase * 8;
  const unsigned short* gB = xt + (n0 + sr) * 256 + sbase * 8;
  floatx4 zf = {0.f, 0.f, 0.f, 0.f};
  floatx4 acc[4][4];
#pragma unroll
  for (int i = 0; i < 4; ++i)
#pragma unroll
    for (int j = 0; j < 4; ++j) acc[i][j] = zf;
  uintx4 ra[4], rb[4];
#define QLOAD(K0) { const uintx4* pa = (const uintx4*)(gA + (K0)); \
                    const uintx4* pb = (const uintx4*)(gB + (K0)); \
                    ra[0] = pa[0]; ra[1] = pa[1]; ra[2] = pa[2]; ra[3] = pa[3]; \
                    rb[0] = pb[0]; rb[1] = pb[1]; rb[2] = pb[2]; rb[3] = pb[3]; }
  QLOAD(0);
#pragma unroll
  for (int ch = 0; ch < 4; ++ch) {
    __syncthreads();
#pragma unroll
    for (int j = 0; j < 4; ++j) {
      *(uintx4*)&As[sr][((sbase + j) ^ r7) * 8] = ra[j];
      *(uintx4*)&Bs[sr][((sbase + j) ^ r7) * 8] = rb[j];
    }
    __syncthreads();
    if (ch < 3) QLOAD((ch + 1) * 64);
#pragma unroll
    for (int kk = 0; kk < 2; ++kk) {
      short8 af[4], bfr[4];
#pragma unroll
      for (int f = 0; f < 4; ++f) {
        int arow = wr * 64 + f * 16 + l15;
        af[f] = *(const short8*)&As[arow][(((kk << 2) + lhi) ^ (arow & 7)) * 8];
        int brow = wc * 64 + f * 16 + l15;
        bfr[f] = *(const short8*)&Bs[brow][(((kk << 2) + lhi) ^ (brow & 7)) * 8];
      }
#pragma unroll
      for (int fm = 0; fm < 4; ++fm)
#pragma unroll
        for (int fn = 0; fn < 4; ++fn)
          acc[fm][fn] = __builtin_amdgcn_mfma_f32_16x16x32_bf16(af[fm], bfr[fn], acc[fm][fn], 0, 0, 0);
    }
  }
#undef QLOAD
#pragma unroll
  for (int fm = 0; fm < 4; ++fm) {
    int crow = m0 + wr * 64 + fm * 16 + lhi * 4;
#pragma unroll
    for (int rr = 0; rr < 4; ++rr) {
      float bv = bias[crow + rr];
#pragma unroll
      for (int fn = 0; fn < 4; ++fn) {
        int pcol = n0 + wc * 64 + fn * 16 + l15;
        int t = pcol >> 16, p = pcol & 65535;
        qkv[(t * 768 + crow + rr) * 65536 + p] = f2bf(acc[fm][fn][rr] + bv);
      }
    }
  }
}

// ---------------- mask gram / rowsum ----------------
__global__ void k_gram(const float* __restrict__ m, float* __restrict__ G) {
  int gw = blockIdx.x * 4 + (threadIdx.x >> 6);
  int lane = threadIdx.x & 63;
  int sc, pair, soff;
  if (gw < 64)         { sc = 0; pair = gw;          soff = 0; }
  else if (gw < 1088)  { sc = 1; pair = gw - 64;     soff = 64; }
  else if (gw < 17472) { sc = 2; pair = gw - 1088;   soff = 1088; }
  else                 { sc = 3; pair = gw - 17472;  soff = 17472; }
  int lw = 7 - sc, W = 1 << lw;
  int N = 8 << (2 * sc);
  int n = pair >> (3 + 2 * sc);
  int mm = pair & (N - 1);
  int ptn, spn, ptm, spm;
  patch_row(n, sc, lw, ptn, spn);
  patch_row(mm, sc, lw, ptm, spm);
  int bn = ptn * 65536 + spn, bm = ptm * 65536 + spm;
  int S = 1 << (14 - 2 * sc);
  float acc = 0.f;
  for (int s = lane; s < S; s += 64) {
    int hh = s >> lw, ww = s & (W - 1);
    int o = (hh << 8) + ww;
    acc += m[bn + o] * m[bm + o];
  }
  for (int off = 32; off; off >>= 1) acc += __shfl_xor(acc, off);
  if (lane == 0) G[soff + pair] = acc;
}

__global__ void k_rsum(const float* __restrict__ m, float* __restrict__ rbuf) {
  int row = blockIdx.x, lane = threadIdx.x;
  int sc, n;
  if (row < 8)        { sc = 0; n = row; }
  else if (row < 40)  { sc = 1; n = row - 8; }
  else if (row < 168) { sc = 2; n = row - 40; }
  else                { sc = 3; n = row - 168; }
  int lw = 7 - sc, W = 1 << lw;
  int pt, sp0;
  patch_row(n, sc, lw, pt, sp0);
  int base = pt * 65536 + sp0;
  int S = 1 << (14 - 2 * sc);
  float acc = 0.f;
  for (int s = lane; s < S; s += 64) {
    int hh = s >> lw, ww = s & (W - 1);
    acc += m[base + (hh << 8) + ww];
  }
  for (int off = 32; off; off >>= 1) acc += __shfl_xor(acc, off);
  if (lane == 0) rbuf[row] = acc;
}

// ---------------- scores GEMM (K-split, atomic accumulate) ----------------
__global__ __launch_bounds__(256) void k_scores(const unsigned short* __restrict__ qkv,
                                                float* __restrict__ scores,
                                                int sc, int soff, int ksteps) {
  int lw = 7 - sc, W = 1 << lw;
  int lS = 14 - 2 * sc;
  int N = 8 << (2 * sc);
  int n0 = blockIdx.x * 32, m0 = blockIdx.y * 32;
  int kbase = blockIdx.z * (ksteps * 32);
  __shared__ __align__(16) unsigned short As[32][40];
  __shared__ __align__(16) unsigned short Bs[32][40];
  int tid = threadIdx.x;
  int w = tid >> 6, l = tid & 63;
  int wr = w >> 1, wc = w & 1;
  floatx4 acc = {0.f, 0.f, 0.f, 0.f};
  bool isA = tid < 128;
  int u = tid & 127;
  int srow = u >> 2, kg = (u & 3) * 8;
  int grow = (isA ? n0 : m0) + srow;
  int cb = (isA ? 0 : 256) + sc * 64;
  int pt = 0, sp0 = 0;
  bool valid = grow < N;
  if (valid) patch_row(grow, sc, lw, pt, sp0);
  uintx4 zu = {0u, 0u, 0u, 0u};

  for (int ks = 0; ks < ksteps; ++ks) {
    int k0 = kbase + ks * 32 + kg;
    uintx4 v = zu;
    if (valid) {
      int cl = k0 >> lS;
      int s = k0 & ((1 << lS) - 1);
      int hh = s >> lw, ww = s & (W - 1);
      int addr = (pt * 768 + cb + cl) * 65536 + sp0 + (hh << 8) + ww;
      v = *(const uintx4*)(qkv + addr);
    }
    __syncthreads();
    if (isA) *(uintx4*)&As[srow][kg] = v;
    else     *(uintx4*)&Bs[srow][kg] = v;
    __syncthreads();
    int koff = (l >> 4) * 8;
    short8 a = *(const short8*)&As[wr * 16 + (l & 15)][koff];
    short8 b = *(const short8*)&Bs[wc * 16 + (l & 15)][koff];
    acc = __builtin_amdgcn_mfma_f32_16x16x32_bf16(a, b, acc, 0, 0, 0);
  }
  int rrow = n0 + wr * 16 + (l >> 4) * 4;
  int ccol = m0 + wc * 16 + (l & 15);
  if (ccol < N) {
#pragma unroll
    for (int rr = 0; rr < 4; ++rr)
      if (rrow + rr < N) atomicAdd(&scores[soff + (rrow + rr) * N + ccol], acc[rr]);
  }
}

// ---------------- logits + softmax -> P bf16 ----------------
__global__ void k_softmax(const float* __restrict__ scores, const float* __restrict__ G,
                          const float* __restrict__ rbuf, const float* __restrict__ msc,
                          unsigned short* __restrict__ pbuf) {
  int row = blockIdx.x, lane = threadIdx.x;
  int sc, n, roff, soff, poff;
  if (row < 8)        { sc = 0; n = row;       roff = 0;   soff = 0;     poff = 0; }
  else if (row < 40)  { sc = 1; n = row - 8;   roff = 8;   soff = 64;    poff = 512; }
  else if (row < 168) { sc = 2; n = row - 40;  roff = 40;  soff = 1088;  poff = 1536; }
  else                { sc = 3; n = row - 168; roff = 168; soff = 17472; poff = 17920; }
  int N = 8 << (2 * sc);
  int Kpad = (sc < 2) ? 32 : N;
  float Sf = (float)(1 << (14 - 2 * sc));
  float invD = 1.0f / (float)(1 << (20 - 2 * sc));
  float alpha = msc[sc * 4 + 0], beta = msc[sc * 4 + 1];
  float gamma = msc[sc * 4 + 2], delta = msc[sc * 4 + 3];
  float rn = rbuf[roff + n];
  float vals[8];
  float mx = -1e30f;
#pragma unroll
  for (int j = 0; j < 8; ++j) {
    float v = -1e30f;
    int mcol = lane + j * 64;
    if (j * 64 < N && mcol < N) {
      float sq = scores[soff + n * N + mcol];
      float g = G[soff + n * N + mcol];
      float rm = rbuf[roff + mcol];
      v = sq * (alpha * g + beta * rn + gamma * rm + delta * Sf) * invD;
    }
    vals[j] = v;
    mx = fmaxf(mx, v);
  }
  for (int off = 32; off; off >>= 1) mx = fmaxf(mx, __shfl_xor(mx, off));
  float sum = 0.f;
#pragma unroll
  for (int j = 0; j < 8; ++j) {
    int mcol = lane + j * 64;
    float e = 0.f;
    if (j * 64 < N && mcol < N) e = __expf(vals[j] - mx);
    vals[j] = e;
    sum += e;
  }
  for (int off = 32; off; off >>= 1) sum += __shfl_xor(sum, off);
  float inv = 1.f / sum;
#pragma unroll
  for (int j = 0; j < 8; ++j) {
    int mcol = lane + j * 64;
    if (j * 64 < N && mcol < N) pbuf[poff + n * Kpad + mcol] = f2bf(vals[j] * inv);
  }
}

// ---------------- PV GEMM: y[n][d] = sum_m P[n][m] V[m][d] -> y_nat ----------------
__global__ __launch_bounds__(256) void k_pv(const unsigned short* __restrict__ qkv,
                                            const unsigned short* __restrict__ pbuf,
                                            unsigned short* __restrict__ ynat,
                                            int sc, int WR, int logWC, int poff) {
  int lw = 7 - sc, W = 1 << lw;
  int lS = 14 - 2 * sc;
  int N = 8 << (2 * sc);
  int Kpad = (sc < 2) ? 32 : N;
  int WC = 1 << logWC;
  int d0 = blockIdx.x * (WC * 64);
  int nb = blockIdx.y * (WR * 16);
  __shared__ __align__(16) unsigned short As[64][40];
  __shared__ __align__(16) unsigned short Bt[256][32];   // [d][m], slot-swizzled
  int tid = threadIdx.x;
  int w = tid >> 6, l = tid & 63;
  int wr = w >> logWC, wc = w & (WC - 1);
  int l15 = l & 15, lhi = l >> 4;
  floatx4 zf = {0.f, 0.f, 0.f, 0.f};
  floatx4 acc[4];
#pragma unroll
  for (int i = 0; i < 4; ++i) acc[i] = zf;
  int bmp = tid & 15;        // m-pair index (m = 2*bmp, 2*bmp+1)
  int dg = tid >> 4;         // 0..15 d-groups of 8
  bool act0 = (WC > 1) || (dg < 8);
  bool has1 = (WC == 4);
  bool doA = tid < WR * 64;
  int arow = tid >> 2, akg = (tid & 3) * 8;
  int ksteps = Kpad >> 5;
  uintx4 zu = {0u, 0u, 0u, 0u};
  int vcb = (512 + sc * 64) * 65536;   // channel base offset for V

  for (int ks = 0; ks < ksteps; ++ks) {
    int k0 = ks * 32;
    uintx4 av = zu;
    if (doA) av = *(const uintx4*)(pbuf + poff + (nb + arow) * Kpad + k0 + akg);
    // V loads: rows gm0/gm1 (m-pair), d-chunks of 8
    int gm0 = k0 + 2 * bmp, gm1 = gm0 + 1;
    bool mv0 = gm0 < N, mv1 = gm1 < N;
    int pt0 = 0, sp00 = 0, pt1 = 0, sp01 = 0;
    if (mv0) patch_row(gm0, sc, lw, pt0, sp00);
    if (mv1) patch_row(gm1, sc, lw, pt1, sp01);
    uintx4 lo0 = zu, hi0 = zu, lo1 = zu, hi1 = zu;
    {
      int du = dg * 8;
      int d = d0 + du;
      int cl = d >> lS;
      int s = d & ((1 << lS) - 1);
      int hh = s >> lw, ww = s & (W - 1);
      int sp = (hh << 8) + ww;
      if (act0 && mv0) lo0 = *(const uintx4*)(qkv + pt0 * 768 * 65536 + vcb + cl * 65536 + sp00 + sp);
      if (act0 && mv1) hi0 = *(const uintx4*)(qkv + pt1 * 768 * 65536 + vcb + cl * 65536 + sp01 + sp);
    }
    if (has1) {
      int du = (dg + 16) * 8;
      int d = d0 + du;
      int cl = d >> lS;
      int s = d & ((1 << lS) - 1);
      int hh = s >> lw, ww = s & (W - 1);
      int sp = (hh << 8) + ww;
      if (mv0) lo1 = *(const uintx4*)(qkv + pt0 * 768 * 65536 + vcb + cl * 65536 + sp00 + sp);
      if (mv1) hi1 = *(const uintx4*)(qkv + pt1 * 768 * 65536 + vcb + cl * 65536 + sp01 + sp);
    }
    __syncthreads();   // previous iteration's MFMA reads done
    if (doA) *(uintx4*)&As[arow][akg] = av;
    if (act0) {
      int du = dg * 8;
#pragma unroll
      for (int j = 0; j < 8; ++j) {
        int d = du + j;
        unsigned losh = (lo0[j >> 1] >> ((j & 1) * 16)) & 0xFFFFu;
        unsigned hish = (hi0[j >> 1] >> ((j & 1) * 16)) & 0xFFFFu;
        unsigned wv = losh | (hish << 16);
        int slot = (bmp >> 2) ^ ((d >> 1) & 3) ^ ((d >> 3) & 3);
        ((unsigned int*)&Bt[d][0])[slot * 4 + (bmp & 3)] = wv;
      }
    }
    if (has1) {
      int du = (dg + 16) * 8;
#pragma unroll
      for (int j = 0; j < 8; ++j) {
        int d = du + j;
        unsigned losh = (lo1[j >> 1] >> ((j & 1) * 16)) & 0xFFFFu;
        unsigned hish = (hi1[j >> 1] >> ((j & 1) * 16)) & 0xFFFFu;
        unsigned wv = losh | (hish << 16);
        int slot = (bmp >> 2) ^ ((d >> 1) & 3) ^ ((d >> 3) & 3);
        ((unsigned int*)&Bt[d][0])[slot * 4 + (bmp & 3)] = wv;
      }
    }
    __syncthreads();
    short8 a = *(const short8*)&As[wr * 16 + l15][lhi * 8];
#pragma unroll
    for (int fn = 0; fn < 4; ++fn) {
      int row = wc * 64 + fn * 16 + l15;
      int slot = lhi ^ ((row >> 1) & 3) ^ ((row >> 3) & 3);
      short8 b = *(const short8*)&Bt[row][slot * 8];
      acc[fn] = __builtin_amdgcn_mfma_f32_16x16x32_bf16(a, b, acc[fn], 0, 0, 0);
    }
  }
  int nrow = nb + wr * 16 + lhi * 4;
#pragma unroll
  for (int rr = 0; rr < 4; ++rr) {
    int n = nrow + rr;
    if (n < N) {
      int pt, sp0;
      patch_row(n, sc, lw, pt, sp0);
#pragma unroll
      for (int fn = 0; fn < 4; ++fn) {
        int d = d0 + wc * 64 + fn * 16 + l15;
        int cl = d >> lS;
        int s = d & ((1 << lS) - 1);
        int hh = s >> lw, ww = s & (W - 1);
        int c = sc * 64 + cl;
        ynat[(pt * 256 + c) * 65536 + sp0 + (hh << 8) + ww] = f2bf(acc[fn][rr]);
      }
    }
  }
}

// ---------------- conv3x3 implicit GEMM (swizzled, chunk 64, prefetch) ----------------
__global__ __launch_bounds__(256) void k_conv(const unsigned short* __restrict__ yt,
                                              const unsigned short* __restrict__ wo,
                                              const float* __restrict__ bo,
                                              float* __restrict__ out) {
  __shared__ __align__(16) unsigned short As[128][64];
  __shared__ __align__(16) unsigned short Bs[128][64];
  int flat = blockIdx.x + (blockIdx.y << 10);          // grid (1024, 2)
  int lg = ((flat & 7) << 8) + (flat >> 3);            // bijective XCD chunking
  int n_t = lg >> 1, m_t = lg & 1;                     // m-inner
  int n0 = n_t << 7, m0 = m_t << 7;
  int tid = threadIdx.x;
  int w = tid >> 6, l = tid & 63;
  int wr = w >> 1, wc = w & 1;
  int l15 = l & 15, lhi = l >> 4;
  int sr = tid >> 1, sbase = (tid & 1) * 4, r7 = sr & 7;
  int p2 = n0 + sr;
  int tt = p2 >> 16, yy = (p2 >> 8) & 255, xx = p2 & 255;
  floatx4 zf = {0.f, 0.f, 0.f, 0.f};
  floatx4 acc[4][4];
#pragma unroll
  for (int i = 0; i < 4; ++i)
#pragma unroll
    for (int j = 0; j < 4; ++j) acc[i][j] = zf;
  uintx4 zu = {0u, 0u, 0u, 0u};
  uintx4 ra[4], rb[4];
#define CLOAD(LC) { int didx = (LC) >> 2; int cc = ((LC) & 3) << 6; \
    int dy3 = (didx * 11) >> 5; int dy = dy3 - 1; int dx = didx - dy3 * 3 - 1; \
    int yq = yy + dy, xq = xx + dx; \
    bool bval = ((unsigned)yq < 256u) && ((unsigned)xq < 256u); \
    const uintx4* pa = (const uintx4*)(wo + didx * 65536 + (m0 + sr) * 256 + cc + sbase * 8); \
    ra[0] = pa[0]; ra[1] = pa[1]; ra[2] = pa[2]; ra[3] = pa[3]; \
    if (bval) { \
      const uintx4* pb = (const uintx4*)(yt + (((tt << 16) + (yq << 8) + xq) << 8) + cc + sbase * 8); \
      rb[0] = pb[0]; rb[1] = pb[1]; rb[2] = pb[2]; rb[3] = pb[3]; \
    } else { rb[0] = zu; rb[1] = zu; rb[2] = zu; rb[3] = zu; } }
  CLOAD(0);
#pragma unroll 4
  for (int lc = 0; lc < 36; ++lc) {
    __syncthreads();
#pragma unroll
    for (int j = 0; j < 4; ++j) {
      *(uintx4*)&As[sr][((sbase + j) ^ r7) * 8] = ra[j];
      *(uintx4*)&Bs[sr][((sbase + j) ^ r7) * 8] = rb[j];
    }
    __syncthreads();
    if (lc < 35) CLOAD(lc + 1);
#pragma unroll
    for (int kk = 0; kk < 2; ++kk) {
      short8 af[4], bfr[4];
#pragma unroll
      for (int f = 0; f < 4; ++f) {
        int arow = wr * 64 + f * 16 + l15;
        af[f] = *(const short8*)&As[arow][(((kk << 2) + lhi) ^ (arow & 7)) * 8];
        int brow = wc * 64 + f * 16 + l15;
        bfr[f] = *(const short8*)&Bs[brow][(((kk << 2) + lhi) ^ (brow & 7)) * 8];
      }
#pragma unroll
      for (int fm = 0; fm < 4; ++fm)
#pragma unroll
        for (int fn = 0; fn < 4; ++fn)
          acc[fm][fn] = __builtin_amdgcn_mfma_f32_16x16x32_bf16(af[fm], bfr[fn], acc[fm][fn], 0, 0, 0);
    }
  }
#undef CLOAD
#pragma unroll
  for (int fm = 0; fm < 4; ++fm) {
    int o = m0 + wr * 64 + fm * 16 + lhi * 4;
#pragma unroll
    for (int rr = 0; rr < 4; ++rr) {
      float bias = bo[o + rr];
#pragma unroll
      for (int fn = 0; fn < 4; ++fn) {
        int p2o = n0 + wc * 64 + fn * 16 + l15;
        int t = p2o >> 16, p = p2o & 65535;
        float z = acc[fm][fn][rr] + bias;
        out[(t * 256 + o + rr) * 65536 + p] = z > 0.f ? z : 0.2f * z;
      }
    }
  }
}

// ---------------------------------------------------------------------------
extern "C" void kernel_launch(void* const* d_in, const int* in_sizes, int n_in,
                              void* d_out, int out_size, void* d_ws, size_t ws_size,
                              hipStream_t stream) {
  const float* x   = (const float*)d_in[0];
  const float* m   = (const float*)d_in[1];
  const float* Wq  = (const float*)d_in[2];
  const float* bq  = (const float*)d_in[3];
  const float* Wk  = (const float*)d_in[4];
  const float* bk  = (const float*)d_in[5];
  const float* Wv  = (const float*)d_in[6];
  const float* bv  = (const float*)d_in[7];
  const float* Wmq = (const float*)d_in[8];
  const float* bmq = (const float*)d_in[9];
  const float* Wmk = (const float*)d_in[10];
  const float* bmk = (const float*)d_in[11];
  const float* Wo  = (const float*)d_in[12];
  const float* bo  = (const float*)d_in[13];

  char* ws = (char*)d_ws;
  unsigned short* qkv   = (unsigned short*)(ws);
  unsigned short* xt    = (unsigned short*)(ws + 201326592);
  unsigned short* wqkv  = (unsigned short*)(ws + 268435456);
  unsigned short* wobf  = (unsigned short*)(ws + 268828672);
  float* bias           = (float*)(ws + 270008320);
  float* msc            = (float*)(ws + 270011392);
  float* scores         = (float*)(ws + 270011456);
  float* G              = (float*)(ws + 271129920);
  float* rbuf           = (float*)(ws + 272248384);
  unsigned short* pbuf  = (unsigned short*)(ws + 272251104);
  float* out            = (float*)d_out;
  unsigned short* ynat  = (unsigned short*)d_out;  // low half of d_out as bf16 scratch
  unsigned short* yt    = xt;                      // reuse x_t space

  k_prep_w<<<dim3(769), dim3(256), 0, stream>>>(Wq, Wk, Wv, bq, bk, bv, Wmq, bmq, Wmk, bmk,
                                                wqkv, bias, msc);
  k_prep_wo<<<dim3(2304), dim3(256), 0, stream>>>(Wo, wobf);
  k_zero<<<dim3(1093), dim3(256), 0, stream>>>(scores, (unsigned int*)pbuf);
  k_xt<<<dim3(1024, 4, 2), dim3(256), 0, stream>>>(x, xt);
  k_qkv<<<dim3(1024, 6), dim3(256), 0, stream>>>(xt, wqkv, bias, qkv);
  k_gram<<<dim3(69904), dim3(256), 0, stream>>>(m, G);
  k_rsum<<<dim3(680), dim3(64), 0, stream>>>(m, rbuf);
  k_scores<<<dim3(1, 1, 1024), dim3(256), 0, stream>>>(qkv, scores, 0, 0, 32);
  k_scores<<<dim3(1, 1, 256), dim3(256), 0, stream>>>(qkv, scores, 1, 64, 32);
  k_scores<<<dim3(4, 4, 64), dim3(256), 0, stream>>>(qkv, scores, 2, 1088, 32);
  k_scores<<<dim3(16, 16, 4), dim3(256), 0, stream>>>(qkv, scores, 3, 17472, 128);
  k_softmax<<<dim3(680), dim3(64), 0, stream>>>(scores, G, rbuf, msc, pbuf);
  k_pv<<<dim3(4096, 1), dim3(256), 0, stream>>>(qkv, pbuf, ynat, 0, 1, 2, 0);
  k_pv<<<dim3(2048, 1), dim3(256), 0, stream>>>(qkv, pbuf, ynat, 1, 2, 1, 512);
  k_pv<<<dim3(1024, 2), dim3(256), 0, stream>>>(qkv, pbuf, ynat, 2, 4, 0, 1536);
  k_pv<<<dim3(256, 8), dim3(256), 0, stream>>>(qkv, pbuf, ynat, 3, 4, 0, 17920);
  k_yt<<<dim3(1024, 4, 2), dim3(256), 0, stream>>>(ynat, yt);
  k_conv<<<dim3(1024, 2), dim3(256), 0, stream>>>(yt, wobf, bo, out);
}

// Round 3
// 616.336 us; speedup vs baseline: 1.2189x; 1.1557x over previous
//
#include <hip/hip_runtime.h>
#include <stdint.h>

// ---------------------------------------------------------------------------
// MultiHeadedAttention (4-scale patch attention) for MI355X / gfx950
// R3: conv 128x256 tile (64 MFMA/wave/stage); scores single-launch K128
//     stages; gram LDS-tiled fp32; pv single-launch; fewer launches (11).
// ---------------------------------------------------------------------------

typedef __attribute__((ext_vector_type(8))) short short8;
typedef __attribute__((ext_vector_type(4))) float floatx4;
typedef __attribute__((ext_vector_type(4))) unsigned int uintx4;

#define DEV static __device__ __forceinline__

DEV unsigned short f2bf(float f) {
  unsigned u = __builtin_bit_cast(unsigned, f);
  unsigned r = u + 0x7FFFu + ((u >> 16) & 1u);
  return (unsigned short)(r >> 16);
}

DEV void patch_row(int n, int sc, int lw, int& pt, int& sp0) {
  pt = n >> (2 + 2 * sc);
  int rem = n & ((4 << (2 * sc)) - 1);
  int oh = rem >> (1 + sc), ow = rem & ((2 << sc) - 1);
  sp0 = (oh << (lw + 8)) + (ow << lw);
}

// ---------------- prep kernels ----------------
__global__ void k_prep_w(const float* __restrict__ Wq, const float* __restrict__ Wk,
                         const float* __restrict__ Wv, const float* __restrict__ bq,
                         const float* __restrict__ bk, const float* __restrict__ bv,
                         const float* __restrict__ Wmq, const float* __restrict__ bmq,
                         const float* __restrict__ Wmk, const float* __restrict__ bmk,
                         unsigned short* __restrict__ wqkv, float* __restrict__ bias,
                         float* __restrict__ msc) {
  int b = blockIdx.x;
  int t = threadIdx.x;
  if (b < 768) {
    const float* src = b < 256 ? (Wq + b * 256) : (b < 512 ? (Wk + (b - 256) * 256)
                                                           : (Wv + (b - 512) * 256));
    wqkv[b * 256 + t] = f2bf(src[t]);
    if (t == 0) bias[b] = b < 256 ? bq[b] : (b < 512 ? bk[b - 256] : bv[b - 512]);
  } else {
    int sc = t >> 6, lane = t & 63;
    int ch = sc * 64 + lane;
    float a0 = Wmq[ch] * Wmk[ch];
    float a1 = Wmq[ch] * bmk[ch];
    float a2 = bmq[ch] * Wmk[ch];
    float a3 = bmq[ch] * bmk[ch];
    for (int off = 32; off; off >>= 1) {
      a0 += __shfl_xor(a0, off); a1 += __shfl_xor(a1, off);
      a2 += __shfl_xor(a2, off); a3 += __shfl_xor(a3, off);
    }
    if (lane == 0) {
      msc[sc * 4 + 0] = a0; msc[sc * 4 + 1] = a1;
      msc[sc * 4 + 2] = a2; msc[sc * 4 + 3] = a3;
    }
  }
}

// Wo repack + zero(scores||G, pbuf) merged
__global__ void k_prep_wo(const float* __restrict__ Wo, unsigned short* __restrict__ wobf,
                          float* __restrict__ scoresG, unsigned int* __restrict__ pbuf) {
  int blk = blockIdx.x;
  if (blk < 2304) {
    int didx = blk >> 8, o = blk & 255, c = threadIdx.x;
    wobf[didx * 65536 + o * 256 + c] = f2bf(Wo[o * 2304 + c * 9 + didx]);
  } else {
    int i = (blk - 2304) * 256 + threadIdx.x;
    if (i < 559232) scoresG[i] = 0.f;
    if (i < 140032) pbuf[i] = 0u;
  }
}

// ---------------- transpose kernels ----------------
__global__ __launch_bounds__(256) void k_xt(const float* __restrict__ x,
                                            unsigned short* __restrict__ xt) {
  __shared__ __align__(16) unsigned short tile[64][72];
  int p0 = blockIdx.x * 64, c0 = blockIdx.y * 64, t = blockIdx.z;
  int tid = threadIdx.x;
  {
    int cc = tid >> 2, pq = (tid & 3) * 16;
    const float* src = x + ((t * 256 + c0 + cc) * 65536 + p0 + pq);
    __align__(16) unsigned short tmp[16];
#pragma unroll
    for (int e = 0; e < 16; e += 4) {
      floatx4 v = *(const floatx4*)(src + e);
      tmp[e + 0] = f2bf(v[0]); tmp[e + 1] = f2bf(v[1]);
      tmp[e + 2] = f2bf(v[2]); tmp[e + 3] = f2bf(v[3]);
    }
    *(uintx4*)&tile[cc][pq] = *(const uintx4*)&tmp[0];
    *(uintx4*)&tile[cc][pq + 8] = *(const uintx4*)&tmp[8];
  }
  __syncthreads();
  {
    int pp = tid >> 2, cg = (tid & 3) * 16;
    __align__(16) unsigned short outv[16];
#pragma unroll
    for (int e = 0; e < 16; ++e) outv[e] = tile[cg + e][pp];
    unsigned short* dst = xt + ((t * 65536 + p0 + pp) * 256 + c0 + cg);
    *(uintx4*)dst = *(const uintx4*)&outv[0];
    *(uintx4*)(dst + 8) = *(const uintx4*)&outv[8];
  }
}

__global__ __launch_bounds__(256) void k_yt(const unsigned short* __restrict__ ynat,
                                            unsigned short* __restrict__ yt) {
  __shared__ __align__(16) unsigned short tile[64][72];
  int p0 = blockIdx.x * 64, c0 = blockIdx.y * 64, t = blockIdx.z;
  int tid = threadIdx.x;
  {
    int cc = tid >> 2, pq = (tid & 3) * 16;
    const unsigned short* src = ynat + ((t * 256 + c0 + cc) * 65536 + p0 + pq);
    *(uintx4*)&tile[cc][pq] = *(const uintx4*)src;
    *(uintx4*)&tile[cc][pq + 8] = *(const uintx4*)(src + 8);
  }
  __syncthreads();
  {
    int pp = tid >> 2, cg = (tid & 3) * 16;
    __align__(16) unsigned short outv[16];
#pragma unroll
    for (int e = 0; e < 16; ++e) outv[e] = tile[cg + e][pp];
    unsigned short* dst = yt + ((t * 65536 + p0 + pp) * 256 + c0 + cg);
    *(uintx4*)dst = *(const uintx4*)&outv[0];
    *(uintx4*)(dst + 8) = *(const uintx4*)&outv[8];
  }
}

// ---------------- QKV GEMM (unchanged from R2) ----------------
__global__ __launch_bounds__(256) void k_qkv(const unsigned short* __restrict__ xt,
                                             const unsigned short* __restrict__ wqkv,
                                             const float* __restrict__ bias,
                                             unsigned short* __restrict__ qkv) {
  __shared__ __align__(16) unsigned short As[128][64];
  __shared__ __align__(16) unsigned short Bs[128][64];
  int flat = blockIdx.x + (blockIdx.y << 10);
  int lg = ((flat & 7) * 768) + (flat >> 3);
  int n_t = lg / 6, m_t = lg - n_t * 6;
  int n0 = n_t << 7, m0 = m_t << 7;
  int tid = threadIdx.x;
  int w = tid >> 6, l = tid & 63;
  int wr = w >> 1, wc = w & 1;
  int l15 = l & 15, lhi = l >> 4;
  int sr = tid >> 1, sbase = (tid & 1) * 4, r7 = sr & 7;
  const unsigned short* gA = wqkv + (m0 + sr) * 256 + sbase * 8;
  const unsigned short* gB = xt + (n0 + sr) * 256 + sbase * 8;
  floatx4 zf = {0.f, 0.f, 0.f, 0.f};
  floatx4 acc[4][4];
#pragma unroll
  for (int i = 0; i < 4; ++i)
#pragma unroll
    for (int j = 0; j < 4; ++j) acc[i][j] = zf;
  uintx4 ra[4], rb[4];
#define QLOAD(K0) { const uintx4* pa = (const uintx4*)(gA + (K0)); \
                    const uintx4* pb = (const uintx4*)(gB + (K0)); \
                    ra[0] = pa[0]; ra[1] = pa[1]; ra[2] = pa[2]; ra[3] = pa[3]; \
                    rb[0] = pb[0]; rb[1] = pb[1]; rb[2] = pb[2]; rb[3] = pb[3]; }
  QLOAD(0);
#pragma unroll
  for (int ch = 0; ch < 4; ++ch) {
    __syncthreads();
#pragma unroll
    for (int j = 0; j < 4; ++j) {
      *(uintx4*)&As[sr][((sbase + j) ^ r7) * 8] = ra[j];
      *(uintx4*)&Bs[sr][((sbase + j) ^ r7) * 8] = rb[j];
    }
    __syncthreads();
    if (ch < 3) QLOAD((ch + 1) * 64);
#pragma unroll
    for (int kk = 0; kk < 2; ++kk) {
      short8 af[4], bfr[4];
#pragma unroll
      for (int f = 0; f < 4; ++f) {
        int arow = wr * 64 + f * 16 + l15;
        af[f] = *(const short8*)&As[arow][(((kk << 2) + lhi) ^ (arow & 7)) * 8];
        int brow = wc * 64 + f * 16 + l15;
        bfr[f] = *(const short8*)&Bs[brow][(((kk << 2) + lhi) ^ (brow & 7)) * 8];
      }
#pragma unroll
      for (int fm = 0; fm < 4; ++fm)
#pragma unroll
        for (int fn = 0; fn < 4; ++fn)
          acc[fm][fn] = __builtin_amdgcn_mfma_f32_16x16x32_bf16(af[fm], bfr[fn], acc[fm][fn], 0, 0, 0);
    }
  }
#undef QLOAD
#pragma unroll
  for (int fm = 0; fm < 4; ++fm) {
    int crow = m0 + wr * 64 + fm * 16 + lhi * 4;
#pragma unroll
    for (int rr = 0; rr < 4; ++rr) {
      float bv = bias[crow + rr];
#pragma unroll
      for (int fn = 0; fn < 4; ++fn) {
        int pcol = n0 + wc * 64 + fn * 16 + l15;
        int t = pcol >> 16, p = pcol & 65535;
        qkv[(t * 768 + crow + rr) * 65536 + p] = f2bf(acc[fm][fn][rr] + bv);
      }
    }
  }
}

// ---------------- mask gram: LDS-tiled fp32, 32x32 pair tiles ----------------
__global__ __launch_bounds__(256) void k_gram2(const float* __restrict__ m,
                                               float* __restrict__ G) {
  __shared__ __align__(16) float Ns[32][68];
  __shared__ __align__(16) float Ms[32][68];
  int bid = blockIdx.x;
  int sc, tn, tm, z, nchunks, soff;
  if (bid < 32)      { sc = 0; tn = 0; tm = 0; z = bid;      nchunks = 8; soff = 0; }
  else if (bid < 40) { sc = 1; tn = 0; tm = 0; z = bid - 32; nchunks = 8; soff = 64; }
  else if (bid < 72) { int r = bid - 40; int tl = r >> 1; sc = 2; tn = tl >> 2; tm = tl & 3; z = r & 1; nchunks = 8; soff = 1088; }
  else               { int tl = bid - 72; sc = 3; tn = tl >> 4; tm = tl & 15; z = 0; nchunks = 4; soff = 17472; }
  int lw = 7 - sc, W = 1 << lw, N = 8 << (2 * sc);
  int kbase = z * nchunks * 64;
  int n0 = tn * 32, m0 = tm * 32;
  int tid = threadIdx.x;
  bool isA = tid < 128;
  int u = tid & 127;
  int srow = u >> 2, sslot0 = (u & 3) * 4;
  int grow = (isA ? n0 : m0) + srow;
  bool valid = grow < N;
  int pt = 0, sp0 = 0;
  if (valid) patch_row(grow, sc, lw, pt, sp0);
  int gbase = pt * 65536 + sp0;
  int trc = tid >> 4, tcc = tid & 15;
  float a00 = 0.f, a01 = 0.f, a10 = 0.f, a11 = 0.f;
  floatx4 zf = {0.f, 0.f, 0.f, 0.f};
  for (int c = 0; c < nchunks; ++c) {
    int k0 = kbase + c * 64;
    floatx4 v[4];
#pragma unroll
    for (int j = 0; j < 4; ++j) {
      v[j] = zf;
      if (valid) {
        int s = k0 + (sslot0 + j) * 4;
        int hh = s >> lw, ww = s & (W - 1);
        v[j] = *(const floatx4*)(m + gbase + (hh << 8) + ww);
      }
    }
    __syncthreads();
    float* dstrow = isA ? &Ns[srow][0] : &Ms[srow][0];
#pragma unroll
    for (int j = 0; j < 4; ++j) *(floatx4*)&dstrow[(sslot0 + j) * 4] = v[j];
    __syncthreads();
#pragma unroll 4
    for (int k = 0; k < 64; k += 4) {
      floatx4 na = *(const floatx4*)&Ns[2 * trc][k];
      floatx4 nb = *(const floatx4*)&Ns[2 * trc + 1][k];
      floatx4 ma = *(const floatx4*)&Ms[2 * tcc][k];
      floatx4 mb = *(const floatx4*)&Ms[2 * tcc + 1][k];
#pragma unroll
      for (int e = 0; e < 4; ++e) {
        a00 += na[e] * ma[e]; a01 += na[e] * mb[e];
        a10 += nb[e] * ma[e]; a11 += nb[e] * mb[e];
      }
    }
  }
  int rn = n0 + 2 * trc, rm = m0 + 2 * tcc;
  float res[2][2] = {{a00, a01}, {a10, a11}};
#pragma unroll
  for (int i = 0; i < 2; ++i)
#pragma unroll
    for (int j = 0; j < 2; ++j) {
      if (rn + i < N && rm + j < N) {
        float* dst = &G[soff + (rn + i) * N + rm + j];
        if (sc < 3) atomicAdd(dst, res[i][j]); else *dst = res[i][j];
      }
    }
}

__global__ void k_rsum(const float* __restrict__ m, float* __restrict__ rbuf) {
  int row = blockIdx.x, lane = threadIdx.x;
  int sc, n;
  if (row < 8)        { sc = 0; n = row; }
  else if (row < 40)  { sc = 1; n = row - 8; }
  else if (row < 168) { sc = 2; n = row - 40; }
  else                { sc = 3; n = row - 168; }
  int lw = 7 - sc, W = 1 << lw;
  int pt, sp0;
  patch_row(n, sc, lw, pt, sp0);
  int base = pt * 65536 + sp0;
  int S = 1 << (14 - 2 * sc);
  float acc = 0.f;
  for (int s = lane; s < S; s += 64) {
    int hh = s >> lw, ww = s & (W - 1);
    acc += m[base + (hh << 8) + ww];
  }
  for (int off = 32; off; off >>= 1) acc += __shfl_xor(acc, off);
  if (lane == 0) rbuf[row] = acc;
}

// ---------------- scores GEMM: single launch, K-chunk 128, 4 MFMA/stage ----------------
__global__ __launch_bounds__(256) void k_scores2(const unsigned short* __restrict__ qkv,
                                                 float* __restrict__ scores) {
  __shared__ __align__(16) unsigned short As[32][136];
  __shared__ __align__(16) unsigned short Bs[32][136];
  int bid = blockIdx.x;
  int sc, tn, tm, z, soff;
  if (bid < 256)      { sc = 0; tn = 0; tm = 0; z = bid;       soff = 0; }
  else if (bid < 320) { sc = 1; tn = 0; tm = 0; z = bid - 256; soff = 64; }
  else if (bid < 576) { int r = bid - 320; int tl = r >> 4; sc = 2; tn = tl >> 2; tm = tl & 3; z = r & 15; soff = 1088; }
  else                { int r = bid - 576; int tl = r >> 2; sc = 3; tn = tl >> 4; tm = tl & 15; z = r & 3; soff = 17472; }
  int lw = 7 - sc, W = 1 << lw, lS = 14 - 2 * sc, N = 8 << (2 * sc);
  int n0 = tn * 32, m0 = tm * 32;
  int kbase = z * 4096;
  int tid = threadIdx.x, w = tid >> 6, l = tid & 63;
  int wr = w >> 1, wc = w & 1, l15 = l & 15, lhi = l >> 4;
  floatx4 acc = {0.f, 0.f, 0.f, 0.f};
  bool isA = tid < 128;
  int u = tid & 127;
  int srow = u >> 2, sslot0 = (u & 3) * 4;
  int grow = (isA ? n0 : m0) + srow;
  int cb = (isA ? 0 : 256) + sc * 64;
  int pt = 0, sp0 = 0;
  bool valid = grow < N;
  if (valid) patch_row(grow, sc, lw, pt, sp0);
  int rowbase = (pt * 768 + cb) * 65536 + sp0;
  uintx4 zu = {0u, 0u, 0u, 0u};
  uintx4 r[4];
#define SLOAD(KS) { int kb2 = kbase + (KS) * 128; \
  _Pragma("unroll") for (int j = 0; j < 4; ++j) { \
    uintx4 v = zu; \
    if (valid) { int k = kb2 + (sslot0 + j) * 8; \
      int cl = k >> lS; int s = k & ((1 << lS) - 1); \
      int hh = s >> lw, ww = s & (W - 1); \
      v = *(const uintx4*)(qkv + rowbase + cl * 65536 + (hh << 8) + ww); } \
    r[j] = v; } }
  SLOAD(0);
  for (int ks = 0; ks < 32; ++ks) {
    __syncthreads();
    {
      unsigned short* dstrow = isA ? &As[srow][0] : &Bs[srow][0];
#pragma unroll
      for (int j = 0; j < 4; ++j) *(uintx4*)&dstrow[(sslot0 + j) * 8] = r[j];
    }
    __syncthreads();
    if (ks < 31) SLOAD(ks + 1);
#pragma unroll
    for (int kk = 0; kk < 4; ++kk) {
      short8 a = *(const short8*)&As[wr * 16 + l15][(kk * 4 + lhi) * 8];
      short8 b = *(const short8*)&Bs[wc * 16 + l15][(kk * 4 + lhi) * 8];
      acc = __builtin_amdgcn_mfma_f32_16x16x32_bf16(a, b, acc, 0, 0, 0);
    }
  }
#undef SLOAD
  int rrow = n0 + wr * 16 + lhi * 4;
  int ccol = m0 + wc * 16 + l15;
  if (ccol < N) {
#pragma unroll
    for (int rr = 0; rr < 4; ++rr)
      if (rrow + rr < N) atomicAdd(&scores[soff + (rrow + rr) * N + ccol], acc[rr]);
  }
}

// ---------------- logits + softmax -> P bf16 ----------------
__global__ void k_softmax(const float* __restrict__ scores, const float* __restrict__ G,
                          const float* __restrict__ rbuf, const float* __restrict__ msc,
                          unsigned short* __restrict__ pbuf) {
  int row = blockIdx.x, lane = threadIdx.x;
  int sc, n, roff, soff, poff;
  if (row < 8)        { sc = 0; n = row;       roff = 0;   soff = 0;     poff = 0; }
  else if (row < 40)  { sc = 1; n = row - 8;   roff = 8;   soff = 64;    poff = 512; }
  else if (row < 168) { sc = 2; n = row - 40;  roff = 40;  soff = 1088;  poff = 1536; }
  else                { sc = 3; n = row - 168; roff = 168; soff = 17472; poff = 17920; }
  int N = 8 << (2 * sc);
  int Kpad = (sc < 2) ? 32 : N;
  float Sf = (float)(1 << (14 - 2 * sc));
  float invD = 1.0f / (float)(1 << (20 - 2 * sc));
  float alpha = msc[sc * 4 + 0], beta = msc[sc * 4 + 1];
  float gamma = msc[sc * 4 + 2], delta = msc[sc * 4 + 3];
  float rn = rbuf[roff + n];
  float vals[8];
  float mx = -1e30f;
#pragma unroll
  for (int j = 0; j < 8; ++j) {
    float v = -1e30f;
    int mcol = lane + j * 64;
    if (j * 64 < N && mcol < N) {
      float sq = scores[soff + n * N + mcol];
      float g = G[soff + n * N + mcol];
      float rm = rbuf[roff + mcol];
      v = sq * (alpha * g + beta * rn + gamma * rm + delta * Sf) * invD;
    }
    vals[j] = v;
    mx = fmaxf(mx, v);
  }
  for (int off = 32; off; off >>= 1) mx = fmaxf(mx, __shfl_xor(mx, off));
  float sum = 0.f;
#pragma unroll
  for (int j = 0; j < 8; ++j) {
    int mcol = lane + j * 64;
    float e = 0.f;
    if (j * 64 < N && mcol < N) e = __expf(vals[j] - mx);
    vals[j] = e;
    sum += e;
  }
  for (int off = 32; off; off >>= 1) sum += __shfl_xor(sum, off);
  float inv = 1.f / sum;
#pragma unroll
  for (int j = 0; j < 8; ++j) {
    int mcol = lane + j * 64;
    if (j * 64 < N && mcol < N) pbuf[poff + n * Kpad + mcol] = f2bf(vals[j] * inv);
  }
}

// ---------------- PV GEMM: single launch, all scales ----------------
__global__ __launch_bounds__(256) void k_pv(const unsigned short* __restrict__ qkv,
                                            const unsigned short* __restrict__ pbuf,
                                            unsigned short* __restrict__ ynat) {
  int bid = blockIdx.x;
  int sc, bx, by;
  if (bid < 4096)      { sc = 0; bx = bid; by = 0; }
  else if (bid < 6144) { sc = 1; bx = bid - 4096; by = 0; }
  else if (bid < 8192) { int r = bid - 6144; sc = 2; bx = r >> 1; by = r & 1; }
  else                 { int r = bid - 8192; sc = 3; bx = r >> 3; by = r & 7; }
  int WR    = (sc == 0) ? 1 : (sc == 1) ? 2 : 4;
  int logWC = (sc == 0) ? 2 : (sc == 1) ? 1 : 0;
  int poff  = (sc == 0) ? 0 : (sc == 1) ? 512 : (sc == 2) ? 1536 : 17920;
  int lw = 7 - sc, W = 1 << lw;
  int lS = 14 - 2 * sc;
  int N = 8 << (2 * sc);
  int Kpad = (sc < 2) ? 32 : N;
  int WC = 1 << logWC;
  int d0 = bx * (WC * 64);
  int nb = by * (WR * 16);
  __shared__ __align__(16) unsigned short As[64][40];
  __shared__ __align__(16) unsigned short Bt[256][32];
  int tid = threadIdx.x;
  int w = tid >> 6, l = tid & 63;
  int wr = w >> logWC, wc = w & (WC - 1);
  int l15 = l & 15, lhi = l >> 4;
  floatx4 zf = {0.f, 0.f, 0.f, 0.f};
  floatx4 acc[4];
#pragma unroll
  for (int i = 0; i < 4; ++i) acc[i] = zf;
  int bmp = tid & 15;
  int dg = tid >> 4;
  bool act0 = (WC > 1) || (dg < 8);
  bool has1 = (WC == 4);
  bool doA = tid < WR * 64;
  int arow = tid >> 2, akg = (tid & 3) * 8;
  int ksteps = Kpad >> 5;
  uintx4 zu = {0u, 0u, 0u, 0u};
  int vcb = (512 + sc * 64) * 65536;

  for (int ks = 0; ks < ksteps; ++ks) {
    int k0 = ks * 32;
    uintx4 av = zu;
    if (doA) av = *(const uintx4*)(pbuf + poff + (nb + arow) * Kpad + k0 + akg);
    int gm0 = k0 + 2 * bmp, gm1 = gm0 + 1;
    bool mv0 = gm0 < N, mv1 = gm1 < N;
    int pt0 = 0, sp00 = 0, pt1 = 0, sp01 = 0;
    if (mv0) patch_row(gm0, sc, lw, pt0, sp00);
    if (mv1) patch_row(gm1, sc, lw, pt1, sp01);
    uintx4 lo0 = zu, hi0 = zu, lo1 = zu, hi1 = zu;
    {
      int d = d0 + dg * 8;
      int cl = d >> lS;
      int s = d & ((1 << lS) - 1);
      int hh = s >> lw, ww = s & (W - 1);
      int sp = (hh << 8) + ww;
      if (act0 && mv0) lo0 = *(const uintx4*)(qkv + pt0 * 768 * 65536 + vcb + cl * 65536 + sp00 + sp);
      if (act0 && mv1) hi0 = *(const uintx4*)(qkv + pt1 * 768 * 65536 + vcb + cl * 65536 + sp01 + sp);
    }
    if (has1) {
      int d = d0 + (dg + 16) * 8;
      int cl = d >> lS;
      int s = d & ((1 << lS) - 1);
      int hh = s >> lw, ww = s & (W - 1);
      int sp = (hh << 8) + ww;
      if (mv0) lo1 = *(const uintx4*)(qkv + pt0 * 768 * 65536 + vcb + cl * 65536 + sp00 + sp);
      if (mv1) hi1 = *(const uintx4*)(qkv + pt1 * 768 * 65536 + vcb + cl * 65536 + sp01 + sp);
    }
    __syncthreads();
    if (doA) *(uintx4*)&As[arow][akg] = av;
    if (act0) {
      int du = dg * 8;
#pragma unroll
      for (int j = 0; j < 8; ++j) {
        int d = du + j;
        unsigned losh = (lo0[j >> 1] >> ((j & 1) * 16)) & 0xFFFFu;
        unsigned hish = (hi0[j >> 1] >> ((j & 1) * 16)) & 0xFFFFu;
        unsigned wv = losh | (hish << 16);
        int slot = (bmp >> 2) ^ ((d >> 1) & 3) ^ ((d >> 3) & 3);
        ((unsigned int*)&Bt[d][0])[slot * 4 + (bmp & 3)] = wv;
      }
    }
    if (has1) {
      int du = (dg + 16) * 8;
#pragma unroll
      for (int j = 0; j < 8; ++j) {
        int d = du + j;
        unsigned losh = (lo1[j >> 1] >> ((j & 1) * 16)) & 0xFFFFu;
        unsigned hish = (hi1[j >> 1] >> ((j & 1) * 16)) & 0xFFFFu;
        unsigned wv = losh | (hish << 16);
        int slot = (bmp >> 2) ^ ((d >> 1) & 3) ^ ((d >> 3) & 3);
        ((unsigned int*)&Bt[d][0])[slot * 4 + (bmp & 3)] = wv;
      }
    }
    __syncthreads();
    short8 a = *(const short8*)&As[wr * 16 + l15][lhi * 8];
#pragma unroll
    for (int fn = 0; fn < 4; ++fn) {
      int row = wc * 64 + fn * 16 + l15;
      int slot = lhi ^ ((row >> 1) & 3) ^ ((row >> 3) & 3);
      short8 b = *(const short8*)&Bt[row][slot * 8];
      acc[fn] = __builtin_amdgcn_mfma_f32_16x16x32_bf16(a, b, acc[fn], 0, 0, 0);
    }
    __syncthreads();
  }
  int nrow = nb + wr * 16 + lhi * 4;
#pragma unroll
  for (int rr = 0; rr < 4; ++rr) {
    int n = nrow + rr;
    if (n < N) {
      int pt, sp0;
      patch_row(n, sc, lw, pt, sp0);
#pragma unroll
      for (int fn = 0; fn < 4; ++fn) {
        int d = d0 + wc * 64 + fn * 16 + l15;
        int cl = d >> lS;
        int s = d & ((1 << lS) - 1);
        int hh = s >> lw, ww = s & (W - 1);
        int c = sc * 64 + cl;
        ynat[(pt * 256 + c) * 65536 + sp0 + (hh << 8) + ww] = f2bf(acc[fn][rr]);
      }
    }
  }
}

// ---------------- conv3x3 implicit GEMM: 128x256 tile, 64 MFMA/wave/stage ----------------
__global__ __launch_bounds__(256, 2) void k_conv(const unsigned short* __restrict__ yt,
                                                 const unsigned short* __restrict__ wo,
                                                 const float* __restrict__ bo,
                                                 float* __restrict__ out) {
  __shared__ __align__(16) unsigned short As[128][64];
  __shared__ __align__(16) unsigned short Bs[256][64];
  int flat = blockIdx.x;                       // 1024 blocks
  int lg = ((flat & 7) << 7) + (flat >> 3);    // bijective XCD chunking (8 x 128)
  int n_t = lg >> 1, m_t = lg & 1;             // m-inner: share B tile on-XCD
  int n0 = n_t << 8, m0 = m_t << 7;            // n-tile = one full image row
  int tt = n0 >> 16, yy = (n0 >> 8) & 255;
  int tid = threadIdx.x;
  int w = tid >> 6, l = tid & 63;
  int wr = w >> 1, wc = w & 1;
  int l15 = l & 15, lhi = l >> 4;
  int arow = tid >> 1, ahalf = tid & 1;        // A staging: 2 threads/row
  floatx4 zf = {0.f, 0.f, 0.f, 0.f};
  floatx4 acc[4][8];
#pragma unroll
  for (int i = 0; i < 4; ++i)
#pragma unroll
    for (int j = 0; j < 8; ++j) acc[i][j] = zf;
  uintx4 zu = {0u, 0u, 0u, 0u};
  uintx4 rb[8];
  // B staging: thread tid owns p2-row x=tid; loads shifted (yq, xq) row, 64ch chunk
#define CLOADB(LC) { int didx = (LC) >> 2; int cc = ((LC) & 3) << 6; \
    int dy3 = (didx * 11) >> 5; int dy = dy3 - 1; int dx = didx - dy3 * 3 - 1; \
    int yq = yy + dy, xq = tid + dx; \
    if (((unsigned)yq < 256u) && ((unsigned)xq < 256u)) { \
      const uintx4* pb = (const uintx4*)(yt + ((((tt << 8) + yq) << 8) + xq) * 256 + cc); \
      rb[0] = pb[0]; rb[1] = pb[1]; rb[2] = pb[2]; rb[3] = pb[3]; \
      rb[4] = pb[4]; rb[5] = pb[5]; rb[6] = pb[6]; rb[7] = pb[7]; \
    } else { rb[0] = zu; rb[1] = zu; rb[2] = zu; rb[3] = zu; \
             rb[4] = zu; rb[5] = zu; rb[6] = zu; rb[7] = zu; } }
  CLOADB(0);
  for (int s = 0; s < 36; ++s) {
    __syncthreads();
    {
      int r7 = tid & 7;
#pragma unroll
      for (int j = 0; j < 8; ++j)
        *(uintx4*)&Bs[tid][(j ^ r7) * 8] = rb[j];
      // A just-in-time (L2-hot weights)
      int didx = s >> 2, cc = (s & 3) << 6;
      const uintx4* pa = (const uintx4*)(wo + didx * 65536 + (m0 + arow) * 256 + cc + ahalf * 32);
      uintx4 ra0 = pa[0], ra1 = pa[1], ra2 = pa[2], ra3 = pa[3];
      int a7 = arow & 7;
      *(uintx4*)&As[arow][((ahalf * 4 + 0) ^ a7) * 8] = ra0;
      *(uintx4*)&As[arow][((ahalf * 4 + 1) ^ a7) * 8] = ra1;
      *(uintx4*)&As[arow][((ahalf * 4 + 2) ^ a7) * 8] = ra2;
      *(uintx4*)&As[arow][((ahalf * 4 + 3) ^ a7) * 8] = ra3;
    }
    __syncthreads();
    if (s < 35) CLOADB(s + 1);
#pragma unroll
    for (int kk = 0; kk < 2; ++kk) {
      short8 af[4];
#pragma unroll
      for (int f = 0; f < 4; ++f) {
        int ar = wr * 64 + f * 16 + l15;
        af[f] = *(const short8*)&As[ar][(((kk << 2) + lhi) ^ (ar & 7)) * 8];
      }
#pragma unroll
      for (int fn = 0; fn < 8; ++fn) {
        int br = wc * 128 + fn * 16 + l15;
        short8 b = *(const short8*)&Bs[br][(((kk << 2) + lhi) ^ (br & 7)) * 8];
#pragma unroll
        for (int fm = 0; fm < 4; ++fm)
          acc[fm][fn] = __builtin_amdgcn_mfma_f32_16x16x32_bf16(af[fm], b, acc[fm][fn], 0, 0, 0);
      }
    }
  }
#undef CLOADB
#pragma unroll
  for (int fm = 0; fm < 4; ++fm) {
    int o = m0 + wr * 64 + fm * 16 + lhi * 4;
#pragma unroll
    for (int rr = 0; rr < 4; ++rr) {
      float bias = bo[o + rr];
#pragma unroll
      for (int fn = 0; fn < 8; ++fn) {
        int xcol = wc * 128 + fn * 16 + l15;
        float z = acc[fm][fn][rr] + bias;
        out[((tt * 256 + o + rr) << 16) + (yy << 8) + xcol] = z > 0.f ? z : 0.2f * z;
      }
    }
  }
}

// ---------------------------------------------------------------------------
extern "C" void kernel_launch(void* const* d_in, const int* in_sizes, int n_in,
                              void* d_out, int out_size, void* d_ws, size_t ws_size,
                              hipStream_t stream) {
  const float* x   = (const float*)d_in[0];
  const float* m   = (const float*)d_in[1];
  const float* Wq  = (const float*)d_in[2];
  const float* bq  = (const float*)d_in[3];
  const float* Wk  = (const float*)d_in[4];
  const float* bk  = (const float*)d_in[5];
  const float* Wv  = (const float*)d_in[6];
  const float* bv  = (const float*)d_in[7];
  const float* Wmq = (const float*)d_in[8];
  const float* bmq = (const float*)d_in[9];
  const float* Wmk = (const float*)d_in[10];
  const float* bmk = (const float*)d_in[11];
  const float* Wo  = (const float*)d_in[12];
  const float* bo  = (const float*)d_in[13];

  char* ws = (char*)d_ws;
  unsigned short* qkv   = (unsigned short*)(ws);
  unsigned short* xt    = (unsigned short*)(ws + 201326592);
  unsigned short* wqkv  = (unsigned short*)(ws + 268435456);
  unsigned short* wobf  = (unsigned short*)(ws + 268828672);
  float* bias           = (float*)(ws + 270008320);
  float* msc            = (float*)(ws + 270011392);
  float* scores         = (float*)(ws + 270011456);
  float* G              = (float*)(ws + 271129920);
  float* rbuf           = (float*)(ws + 272248384);
  unsigned short* pbuf  = (unsigned short*)(ws + 272251104);
  float* out            = (float*)d_out;
  unsigned short* ynat  = (unsigned short*)d_out;  // low half of d_out as bf16 scratch
  unsigned short* yt    = xt;                      // reuse x_t space

  k_prep_w<<<dim3(769), dim3(256), 0, stream>>>(Wq, Wk, Wv, bq, bk, bv, Wmq, bmq, Wmk, bmk,
                                                wqkv, bias, msc);
  k_prep_wo<<<dim3(4489), dim3(256), 0, stream>>>(Wo, wobf, scores, (unsigned int*)pbuf);
  k_xt<<<dim3(1024, 4, 2), dim3(256), 0, stream>>>(x, xt);
  k_qkv<<<dim3(1024, 6), dim3(256), 0, stream>>>(xt, wqkv, bias, qkv);
  k_gram2<<<dim3(328), dim3(256), 0, stream>>>(m, G);
  k_rsum<<<dim3(680), dim3(64), 0, stream>>>(m, rbuf);
  k_scores2<<<dim3(1600), dim3(256), 0, stream>>>(qkv, scores);
  k_softmax<<<dim3(680), dim3(64), 0, stream>>>(scores, G, rbuf, msc, pbuf);
  k_pv<<<dim3(10240), dim3(256), 0, stream>>>(qkv, pbuf, ynat);
  k_yt<<<dim3(1024, 4, 2), dim3(256), 0, stream>>>(ynat, yt);
  k_conv<<<dim3(1024), dim3(256), 0, stream>>>(yt, wobf, bo, out);
}

// Round 4
// 568.415 us; speedup vs baseline: 1.3217x; 1.0843x over previous
//
#include <hip/hip_runtime.h>
#include <stdint.h>

// ---------------------------------------------------------------------------
// MultiHeadedAttention (4-scale patch attention) for MI355X / gfx950
// R4: k_conv rewritten — halo-row staging (3 rows staged once per ch-chunk,
//     all 9 taps consume via LDS row shift), 24 stages x 96 MFMA/wave,
//     reg-prefetched A and B, proven XOR slot swizzles. Rest = R3.
// ---------------------------------------------------------------------------

typedef __attribute__((ext_vector_type(8))) short short8;
typedef __attribute__((ext_vector_type(4))) float floatx4;
typedef __attribute__((ext_vector_type(4))) unsigned int uintx4;

#define DEV static __device__ __forceinline__

DEV unsigned short f2bf(float f) {
  unsigned u = __builtin_bit_cast(unsigned, f);
  unsigned r = u + 0x7FFFu + ((u >> 16) & 1u);
  return (unsigned short)(r >> 16);
}

DEV void patch_row(int n, int sc, int lw, int& pt, int& sp0) {
  pt = n >> (2 + 2 * sc);
  int rem = n & ((4 << (2 * sc)) - 1);
  int oh = rem >> (1 + sc), ow = rem & ((2 << sc) - 1);
  sp0 = (oh << (lw + 8)) + (ow << lw);
}

// ---------------- prep kernels ----------------
__global__ void k_prep_w(const float* __restrict__ Wq, const float* __restrict__ Wk,
                         const float* __restrict__ Wv, const float* __restrict__ bq,
                         const float* __restrict__ bk, const float* __restrict__ bv,
                         const float* __restrict__ Wmq, const float* __restrict__ bmq,
                         const float* __restrict__ Wmk, const float* __restrict__ bmk,
                         unsigned short* __restrict__ wqkv, float* __restrict__ bias,
                         float* __restrict__ msc) {
  int b = blockIdx.x;
  int t = threadIdx.x;
  if (b < 768) {
    const float* src = b < 256 ? (Wq + b * 256) : (b < 512 ? (Wk + (b - 256) * 256)
                                                           : (Wv + (b - 512) * 256));
    wqkv[b * 256 + t] = f2bf(src[t]);
    if (t == 0) bias[b] = b < 256 ? bq[b] : (b < 512 ? bk[b - 256] : bv[b - 512]);
  } else {
    int sc = t >> 6, lane = t & 63;
    int ch = sc * 64 + lane;
    float a0 = Wmq[ch] * Wmk[ch];
    float a1 = Wmq[ch] * bmk[ch];
    float a2 = bmq[ch] * Wmk[ch];
    float a3 = bmq[ch] * bmk[ch];
    for (int off = 32; off; off >>= 1) {
      a0 += __shfl_xor(a0, off); a1 += __shfl_xor(a1, off);
      a2 += __shfl_xor(a2, off); a3 += __shfl_xor(a3, off);
    }
    if (lane == 0) {
      msc[sc * 4 + 0] = a0; msc[sc * 4 + 1] = a1;
      msc[sc * 4 + 2] = a2; msc[sc * 4 + 3] = a3;
    }
  }
}

// Wo repack + zero(scores||G, pbuf) merged
__global__ void k_prep_wo(const float* __restrict__ Wo, unsigned short* __restrict__ wobf,
                          float* __restrict__ scoresG, unsigned int* __restrict__ pbuf) {
  int blk = blockIdx.x;
  if (blk < 2304) {
    int didx = blk >> 8, o = blk & 255, c = threadIdx.x;
    wobf[didx * 65536 + o * 256 + c] = f2bf(Wo[o * 2304 + c * 9 + didx]);
  } else {
    int i = (blk - 2304) * 256 + threadIdx.x;
    if (i < 559232) scoresG[i] = 0.f;
    if (i < 140032) pbuf[i] = 0u;
  }
}

// ---------------- transpose kernels ----------------
__global__ __launch_bounds__(256) void k_xt(const float* __restrict__ x,
                                            unsigned short* __restrict__ xt) {
  __shared__ __align__(16) unsigned short tile[64][72];
  int p0 = blockIdx.x * 64, c0 = blockIdx.y * 64, t = blockIdx.z;
  int tid = threadIdx.x;
  {
    int cc = tid >> 2, pq = (tid & 3) * 16;
    const float* src = x + ((t * 256 + c0 + cc) * 65536 + p0 + pq);
    __align__(16) unsigned short tmp[16];
#pragma unroll
    for (int e = 0; e < 16; e += 4) {
      floatx4 v = *(const floatx4*)(src + e);
      tmp[e + 0] = f2bf(v[0]); tmp[e + 1] = f2bf(v[1]);
      tmp[e + 2] = f2bf(v[2]); tmp[e + 3] = f2bf(v[3]);
    }
    *(uintx4*)&tile[cc][pq] = *(const uintx4*)&tmp[0];
    *(uintx4*)&tile[cc][pq + 8] = *(const uintx4*)&tmp[8];
  }
  __syncthreads();
  {
    int pp = tid >> 2, cg = (tid & 3) * 16;
    __align__(16) unsigned short outv[16];
#pragma unroll
    for (int e = 0; e < 16; ++e) outv[e] = tile[cg + e][pp];
    unsigned short* dst = xt + ((t * 65536 + p0 + pp) * 256 + c0 + cg);
    *(uintx4*)dst = *(const uintx4*)&outv[0];
    *(uintx4*)(dst + 8) = *(const uintx4*)&outv[8];
  }
}

__global__ __launch_bounds__(256) void k_yt(const unsigned short* __restrict__ ynat,
                                            unsigned short* __restrict__ yt) {
  __shared__ __align__(16) unsigned short tile[64][72];
  int p0 = blockIdx.x * 64, c0 = blockIdx.y * 64, t = blockIdx.z;
  int tid = threadIdx.x;
  {
    int cc = tid >> 2, pq = (tid & 3) * 16;
    const unsigned short* src = ynat + ((t * 256 + c0 + cc) * 65536 + p0 + pq);
    *(uintx4*)&tile[cc][pq] = *(const uintx4*)src;
    *(uintx4*)&tile[cc][pq + 8] = *(const uintx4*)(src + 8);
  }
  __syncthreads();
  {
    int pp = tid >> 2, cg = (tid & 3) * 16;
    __align__(16) unsigned short outv[16];
#pragma unroll
    for (int e = 0; e < 16; ++e) outv[e] = tile[cg + e][pp];
    unsigned short* dst = yt + ((t * 65536 + p0 + pp) * 256 + c0 + cg);
    *(uintx4*)dst = *(const uintx4*)&outv[0];
    *(uintx4*)(dst + 8) = *(const uintx4*)&outv[8];
  }
}

// ---------------- QKV GEMM ----------------
__global__ __launch_bounds__(256) void k_qkv(const unsigned short* __restrict__ xt,
                                             const unsigned short* __restrict__ wqkv,
                                             const float* __restrict__ bias,
                                             unsigned short* __restrict__ qkv) {
  __shared__ __align__(16) unsigned short As[128][64];
  __shared__ __align__(16) unsigned short Bs[128][64];
  int flat = blockIdx.x + (blockIdx.y << 10);
  int lg = ((flat & 7) * 768) + (flat >> 3);
  int n_t = lg / 6, m_t = lg - n_t * 6;
  int n0 = n_t << 7, m0 = m_t << 7;
  int tid = threadIdx.x;
  int w = tid >> 6, l = tid & 63;
  int wr = w >> 1, wc = w & 1;
  int l15 = l & 15, lhi = l >> 4;
  int sr = tid >> 1, sbase = (tid & 1) * 4, r7 = sr & 7;
  const unsigned short* gA = wqkv + (m0 + sr) * 256 + sbase * 8;
  const unsigned short* gB = xt + (n0 + sr) * 256 + sbase * 8;
  floatx4 zf = {0.f, 0.f, 0.f, 0.f};
  floatx4 acc[4][4];
#pragma unroll
  for (int i = 0; i < 4; ++i)
#pragma unroll
    for (int j = 0; j < 4; ++j) acc[i][j] = zf;
  uintx4 ra[4], rb[4];
#define QLOAD(K0) { const uintx4* pa = (const uintx4*)(gA + (K0)); \
                    const uintx4* pb = (const uintx4*)(gB + (K0)); \
                    ra[0] = pa[0]; ra[1] = pa[1]; ra[2] = pa[2]; ra[3] = pa[3]; \
                    rb[0] = pb[0]; rb[1] = pb[1]; rb[2] = pb[2]; rb[3] = pb[3]; }
  QLOAD(0);
#pragma unroll
  for (int ch = 0; ch < 4; ++ch) {
    __syncthreads();
#pragma unroll
    for (int j = 0; j < 4; ++j) {
      *(uintx4*)&As[sr][((sbase + j) ^ r7) * 8] = ra[j];
      *(uintx4*)&Bs[sr][((sbase + j) ^ r7) * 8] = rb[j];
    }
    __syncthreads();
    if (ch < 3) QLOAD((ch + 1) * 64);
#pragma unroll
    for (int kk = 0; kk < 2; ++kk) {
      short8 af[4], bfr[4];
#pragma unroll
      for (int f = 0; f < 4; ++f) {
        int arow = wr * 64 + f * 16 + l15;
        af[f] = *(const short8*)&As[arow][(((kk << 2) + lhi) ^ (arow & 7)) * 8];
        int brow = wc * 64 + f * 16 + l15;
        bfr[f] = *(const short8*)&Bs[brow][(((kk << 2) + lhi) ^ (brow & 7)) * 8];
      }
#pragma unroll
      for (int fm = 0; fm < 4; ++fm)
#pragma unroll
        for (int fn = 0; fn < 4; ++fn)
          acc[fm][fn] = __builtin_amdgcn_mfma_f32_16x16x32_bf16(af[fm], bfr[fn], acc[fm][fn], 0, 0, 0);
    }
  }
#undef QLOAD
#pragma unroll
  for (int fm = 0; fm < 4; ++fm) {
    int crow = m0 + wr * 64 + fm * 16 + lhi * 4;
#pragma unroll
    for (int rr = 0; rr < 4; ++rr) {
      float bv = bias[crow + rr];
#pragma unroll
      for (int fn = 0; fn < 4; ++fn) {
        int pcol = n0 + wc * 64 + fn * 16 + l15;
        int t = pcol >> 16, p = pcol & 65535;
        qkv[(t * 768 + crow + rr) * 65536 + p] = f2bf(acc[fm][fn][rr] + bv);
      }
    }
  }
}

// ---------------- mask gram: LDS-tiled fp32, 32x32 pair tiles ----------------
__global__ __launch_bounds__(256) void k_gram2(const float* __restrict__ m,
                                               float* __restrict__ G) {
  __shared__ __align__(16) float Ns[32][68];
  __shared__ __align__(16) float Ms[32][68];
  int bid = blockIdx.x;
  int sc, tn, tm, z, nchunks, soff;
  if (bid < 32)      { sc = 0; tn = 0; tm = 0; z = bid;      nchunks = 8; soff = 0; }
  else if (bid < 40) { sc = 1; tn = 0; tm = 0; z = bid - 32; nchunks = 8; soff = 64; }
  else if (bid < 72) { int r = bid - 40; int tl = r >> 1; sc = 2; tn = tl >> 2; tm = tl & 3; z = r & 1; nchunks = 8; soff = 1088; }
  else               { int tl = bid - 72; sc = 3; tn = tl >> 4; tm = tl & 15; z = 0; nchunks = 4; soff = 17472; }
  int lw = 7 - sc, W = 1 << lw, N = 8 << (2 * sc);
  int kbase = z * nchunks * 64;
  int n0 = tn * 32, m0 = tm * 32;
  int tid = threadIdx.x;
  bool isA = tid < 128;
  int u = tid & 127;
  int srow = u >> 2, sslot0 = (u & 3) * 4;
  int grow = (isA ? n0 : m0) + srow;
  bool valid = grow < N;
  int pt = 0, sp0 = 0;
  if (valid) patch_row(grow, sc, lw, pt, sp0);
  int gbase = pt * 65536 + sp0;
  int trc = tid >> 4, tcc = tid & 15;
  float a00 = 0.f, a01 = 0.f, a10 = 0.f, a11 = 0.f;
  floatx4 zf = {0.f, 0.f, 0.f, 0.f};
  for (int c = 0; c < nchunks; ++c) {
    int k0 = kbase + c * 64;
    floatx4 v[4];
#pragma unroll
    for (int j = 0; j < 4; ++j) {
      v[j] = zf;
      if (valid) {
        int s = k0 + (sslot0 + j) * 4;
        int hh = s >> lw, ww = s & (W - 1);
        v[j] = *(const floatx4*)(m + gbase + (hh << 8) + ww);
      }
    }
    __syncthreads();
    float* dstrow = isA ? &Ns[srow][0] : &Ms[srow][0];
#pragma unroll
    for (int j = 0; j < 4; ++j) *(floatx4*)&dstrow[(sslot0 + j) * 4] = v[j];
    __syncthreads();
#pragma unroll 4
    for (int k = 0; k < 64; k += 4) {
      floatx4 na = *(const floatx4*)&Ns[2 * trc][k];
      floatx4 nb = *(const floatx4*)&Ns[2 * trc + 1][k];
      floatx4 ma = *(const floatx4*)&Ms[2 * tcc][k];
      floatx4 mb = *(const floatx4*)&Ms[2 * tcc + 1][k];
#pragma unroll
      for (int e = 0; e < 4; ++e) {
        a00 += na[e] * ma[e]; a01 += na[e] * mb[e];
        a10 += nb[e] * ma[e]; a11 += nb[e] * mb[e];
      }
    }
  }
  int rn = n0 + 2 * trc, rm = m0 + 2 * tcc;
  float res[2][2] = {{a00, a01}, {a10, a11}};
#pragma unroll
  for (int i = 0; i < 2; ++i)
#pragma unroll
    for (int j = 0; j < 2; ++j) {
      if (rn + i < N && rm + j < N) {
        float* dst = &G[soff + (rn + i) * N + rm + j];
        if (sc < 3) atomicAdd(dst, res[i][j]); else *dst = res[i][j];
      }
    }
}

__global__ void k_rsum(const float* __restrict__ m, float* __restrict__ rbuf) {
  int row = blockIdx.x, lane = threadIdx.x;
  int sc, n;
  if (row < 8)        { sc = 0; n = row; }
  else if (row < 40)  { sc = 1; n = row - 8; }
  else if (row < 168) { sc = 2; n = row - 40; }
  else                { sc = 3; n = row - 168; }
  int lw = 7 - sc, W = 1 << lw;
  int pt, sp0;
  patch_row(n, sc, lw, pt, sp0);
  int base = pt * 65536 + sp0;
  int S = 1 << (14 - 2 * sc);
  float acc = 0.f;
  for (int s = lane; s < S; s += 64) {
    int hh = s >> lw, ww = s & (W - 1);
    acc += m[base + (hh << 8) + ww];
  }
  for (int off = 32; off; off >>= 1) acc += __shfl_xor(acc, off);
  if (lane == 0) rbuf[row] = acc;
}

// ---------------- scores GEMM: single launch, K-chunk 128, 4 MFMA/stage ----------------
__global__ __launch_bounds__(256) void k_scores2(const unsigned short* __restrict__ qkv,
                                                 float* __restrict__ scores) {
  __shared__ __align__(16) unsigned short As[32][136];
  __shared__ __align__(16) unsigned short Bs[32][136];
  int bid = blockIdx.x;
  int sc, tn, tm, z, soff;
  if (bid < 256)      { sc = 0; tn = 0; tm = 0; z = bid;       soff = 0; }
  else if (bid < 320) { sc = 1; tn = 0; tm = 0; z = bid - 256; soff = 64; }
  else if (bid < 576) { int r = bid - 320; int tl = r >> 4; sc = 2; tn = tl >> 2; tm = tl & 3; z = r & 15; soff = 1088; }
  else                { int r = bid - 576; int tl = r >> 2; sc = 3; tn = tl >> 4; tm = tl & 15; z = r & 3; soff = 17472; }
  int lw = 7 - sc, W = 1 << lw, lS = 14 - 2 * sc, N = 8 << (2 * sc);
  int n0 = tn * 32, m0 = tm * 32;
  int kbase = z * 4096;
  int tid = threadIdx.x, w = tid >> 6, l = tid & 63;
  int wr = w >> 1, wc = w & 1, l15 = l & 15, lhi = l >> 4;
  floatx4 acc = {0.f, 0.f, 0.f, 0.f};
  bool isA = tid < 128;
  int u = tid & 127;
  int srow = u >> 2, sslot0 = (u & 3) * 4;
  int grow = (isA ? n0 : m0) + srow;
  int cb = (isA ? 0 : 256) + sc * 64;
  int pt = 0, sp0 = 0;
  bool valid = grow < N;
  if (valid) patch_row(grow, sc, lw, pt, sp0);
  int rowbase = (pt * 768 + cb) * 65536 + sp0;
  uintx4 zu = {0u, 0u, 0u, 0u};
  uintx4 r[4];
#define SLOAD(KS) { int kb2 = kbase + (KS) * 128; \
  _Pragma("unroll") for (int j = 0; j < 4; ++j) { \
    uintx4 v = zu; \
    if (valid) { int k = kb2 + (sslot0 + j) * 8; \
      int cl = k >> lS; int s = k & ((1 << lS) - 1); \
      int hh = s >> lw, ww = s & (W - 1); \
      v = *(const uintx4*)(qkv + rowbase + cl * 65536 + (hh << 8) + ww); } \
    r[j] = v; } }
  SLOAD(0);
  for (int ks = 0; ks < 32; ++ks) {
    __syncthreads();
    {
      unsigned short* dstrow = isA ? &As[srow][0] : &Bs[srow][0];
#pragma unroll
      for (int j = 0; j < 4; ++j) *(uintx4*)&dstrow[(sslot0 + j) * 8] = r[j];
    }
    __syncthreads();
    if (ks < 31) SLOAD(ks + 1);
#pragma unroll
    for (int kk = 0; kk < 4; ++kk) {
      short8 a = *(const short8*)&As[wr * 16 + l15][(kk * 4 + lhi) * 8];
      short8 b = *(const short8*)&Bs[wc * 16 + l15][(kk * 4 + lhi) * 8];
      acc = __builtin_amdgcn_mfma_f32_16x16x32_bf16(a, b, acc, 0, 0, 0);
    }
  }
#undef SLOAD
  int rrow = n0 + wr * 16 + lhi * 4;
  int ccol = m0 + wc * 16 + l15;
  if (ccol < N) {
#pragma unroll
    for (int rr = 0; rr < 4; ++rr)
      if (rrow + rr < N) atomicAdd(&scores[soff + (rrow + rr) * N + ccol], acc[rr]);
  }
}

// ---------------- logits + softmax -> P bf16 ----------------
__global__ void k_softmax(const float* __restrict__ scores, const float* __restrict__ G,
                          const float* __restrict__ rbuf, const float* __restrict__ msc,
                          unsigned short* __restrict__ pbuf) {
  int row = blockIdx.x, lane = threadIdx.x;
  int sc, n, roff, soff, poff;
  if (row < 8)        { sc = 0; n = row;       roff = 0;   soff = 0;     poff = 0; }
  else if (row < 40)  { sc = 1; n = row - 8;   roff = 8;   soff = 64;    poff = 512; }
  else if (row < 168) { sc = 2; n = row - 40;  roff = 40;  soff = 1088;  poff = 1536; }
  else                { sc = 3; n = row - 168; roff = 168; soff = 17472; poff = 17920; }
  int N = 8 << (2 * sc);
  int Kpad = (sc < 2) ? 32 : N;
  float Sf = (float)(1 << (14 - 2 * sc));
  float invD = 1.0f / (float)(1 << (20 - 2 * sc));
  float alpha = msc[sc * 4 + 0], beta = msc[sc * 4 + 1];
  float gamma = msc[sc * 4 + 2], delta = msc[sc * 4 + 3];
  float rn = rbuf[roff + n];
  float vals[8];
  float mx = -1e30f;
#pragma unroll
  for (int j = 0; j < 8; ++j) {
    float v = -1e30f;
    int mcol = lane + j * 64;
    if (j * 64 < N && mcol < N) {
      float sq = scores[soff + n * N + mcol];
      float g = G[soff + n * N + mcol];
      float rm = rbuf[roff + mcol];
      v = sq * (alpha * g + beta * rn + gamma * rm + delta * Sf) * invD;
    }
    vals[j] = v;
    mx = fmaxf(mx, v);
  }
  for (int off = 32; off; off >>= 1) mx = fmaxf(mx, __shfl_xor(mx, off));
  float sum = 0.f;
#pragma unroll
  for (int j = 0; j < 8; ++j) {
    int mcol = lane + j * 64;
    float e = 0.f;
    if (j * 64 < N && mcol < N) e = __expf(vals[j] - mx);
    vals[j] = e;
    sum += e;
  }
  for (int off = 32; off; off >>= 1) sum += __shfl_xor(sum, off);
  float inv = 1.f / sum;
#pragma unroll
  for (int j = 0; j < 8; ++j) {
    int mcol = lane + j * 64;
    if (j * 64 < N && mcol < N) pbuf[poff + n * Kpad + mcol] = f2bf(vals[j] * inv);
  }
}

// ---------------- PV GEMM: single launch, all scales ----------------
__global__ __launch_bounds__(256) void k_pv(const unsigned short* __restrict__ qkv,
                                            const unsigned short* __restrict__ pbuf,
                                            unsigned short* __restrict__ ynat) {
  int bid = blockIdx.x;
  int sc, bx, by;
  if (bid < 4096)      { sc = 0; bx = bid; by = 0; }
  else if (bid < 6144) { sc = 1; bx = bid - 4096; by = 0; }
  else if (bid < 8192) { int r = bid - 6144; sc = 2; bx = r >> 1; by = r & 1; }
  else                 { int r = bid - 8192; sc = 3; bx = r >> 3; by = r & 7; }
  int WR    = (sc == 0) ? 1 : (sc == 1) ? 2 : 4;
  int logWC = (sc == 0) ? 2 : (sc == 1) ? 1 : 0;
  int poff  = (sc == 0) ? 0 : (sc == 1) ? 512 : (sc == 2) ? 1536 : 17920;
  int lw = 7 - sc, W = 1 << lw;
  int lS = 14 - 2 * sc;
  int N = 8 << (2 * sc);
  int Kpad = (sc < 2) ? 32 : N;
  int WC = 1 << logWC;
  int d0 = bx * (WC * 64);
  int nb = by * (WR * 16);
  __shared__ __align__(16) unsigned short As[64][40];
  __shared__ __align__(16) unsigned short Bt[256][32];
  int tid = threadIdx.x;
  int w = tid >> 6, l = tid & 63;
  int wr = w >> logWC, wc = w & (WC - 1);
  int l15 = l & 15, lhi = l >> 4;
  floatx4 zf = {0.f, 0.f, 0.f, 0.f};
  floatx4 acc[4];
#pragma unroll
  for (int i = 0; i < 4; ++i) acc[i] = zf;
  int bmp = tid & 15;
  int dg = tid >> 4;
  bool act0 = (WC > 1) || (dg < 8);
  bool has1 = (WC == 4);
  bool doA = tid < WR * 64;
  int arow = tid >> 2, akg = (tid & 3) * 8;
  int ksteps = Kpad >> 5;
  uintx4 zu = {0u, 0u, 0u, 0u};
  int vcb = (512 + sc * 64) * 65536;

  for (int ks = 0; ks < ksteps; ++ks) {
    int k0 = ks * 32;
    uintx4 av = zu;
    if (doA) av = *(const uintx4*)(pbuf + poff + (nb + arow) * Kpad + k0 + akg);
    int gm0 = k0 + 2 * bmp, gm1 = gm0 + 1;
    bool mv0 = gm0 < N, mv1 = gm1 < N;
    int pt0 = 0, sp00 = 0, pt1 = 0, sp01 = 0;
    if (mv0) patch_row(gm0, sc, lw, pt0, sp00);
    if (mv1) patch_row(gm1, sc, lw, pt1, sp01);
    uintx4 lo0 = zu, hi0 = zu, lo1 = zu, hi1 = zu;
    {
      int d = d0 + dg * 8;
      int cl = d >> lS;
      int s = d & ((1 << lS) - 1);
      int hh = s >> lw, ww = s & (W - 1);
      int sp = (hh << 8) + ww;
      if (act0 && mv0) lo0 = *(const uintx4*)(qkv + pt0 * 768 * 65536 + vcb + cl * 65536 + sp00 + sp);
      if (act0 && mv1) hi0 = *(const uintx4*)(qkv + pt1 * 768 * 65536 + vcb + cl * 65536 + sp01 + sp);
    }
    if (has1) {
      int d = d0 + (dg + 16) * 8;
      int cl = d >> lS;
      int s = d & ((1 << lS) - 1);
      int hh = s >> lw, ww = s & (W - 1);
      int sp = (hh << 8) + ww;
      if (mv0) lo1 = *(const uintx4*)(qkv + pt0 * 768 * 65536 + vcb + cl * 65536 + sp00 + sp);
      if (mv1) hi1 = *(const uintx4*)(qkv + pt1 * 768 * 65536 + vcb + cl * 65536 + sp01 + sp);
    }
    __syncthreads();
    if (doA) *(uintx4*)&As[arow][akg] = av;
    if (act0) {
      int du = dg * 8;
#pragma unroll
      for (int j = 0; j < 8; ++j) {
        int d = du + j;
        unsigned losh = (lo0[j >> 1] >> ((j & 1) * 16)) & 0xFFFFu;
        unsigned hish = (hi0[j >> 1] >> ((j & 1) * 16)) & 0xFFFFu;
        unsigned wv = losh | (hish << 16);
        int slot = (bmp >> 2) ^ ((d >> 1) & 3) ^ ((d >> 3) & 3);
        ((unsigned int*)&Bt[d][0])[slot * 4 + (bmp & 3)] = wv;
      }
    }
    if (has1) {
      int du = (dg + 16) * 8;
#pragma unroll
      for (int j = 0; j < 8; ++j) {
        int d = du + j;
        unsigned losh = (lo1[j >> 1] >> ((j & 1) * 16)) & 0xFFFFu;
        unsigned hish = (hi1[j >> 1] >> ((j & 1) * 16)) & 0xFFFFu;
        unsigned wv = losh | (hish << 16);
        int slot = (bmp >> 2) ^ ((d >> 1) & 3) ^ ((d >> 3) & 3);
        ((unsigned int*)&Bt[d][0])[slot * 4 + (bmp & 3)] = wv;
      }
    }
    __syncthreads();
    short8 a = *(const short8*)&As[wr * 16 + l15][lhi * 8];
#pragma unroll
    for (int fn = 0; fn < 4; ++fn) {
      int row = wc * 64 + fn * 16 + l15;
      int slot = lhi ^ ((row >> 1) & 3) ^ ((row >> 3) & 3);
      short8 b = *(const short8*)&Bt[row][slot * 8];
      acc[fn] = __builtin_amdgcn_mfma_f32_16x16x32_bf16(a, b, acc[fn], 0, 0, 0);
    }
    __syncthreads();
  }
  int nrow = nb + wr * 16 + lhi * 4;
#pragma unroll
  for (int rr = 0; rr < 4; ++rr) {
    int n = nrow + rr;
    if (n < N) {
      int pt, sp0;
      patch_row(n, sc, lw, pt, sp0);
#pragma unroll
      for (int fn = 0; fn < 4; ++fn) {
        int d = d0 + wc * 64 + fn * 16 + l15;
        int cl = d >> lS;
        int s = d & ((1 << lS) - 1);
        int hh = s >> lw, ww = s & (W - 1);
        int c = sc * 64 + cl;
        ynat[(pt * 256 + c) * 65536 + sp0 + (hh << 8) + ww] = f2bf(acc[fn][rr]);
      }
    }
  }
}

// ---------------- conv3x3: halo-row staging, 24 stages x 96 MFMA/wave ----------------
// LDS: As[128 o][16 slots]: slot' = (dxTap*4 + chSlot) ^ (o&7)      (32 KB)
//      Bs[130 xq-pair][8 slots]: slot' = ((xh&1)*4 + chSlot) ^ ((xh>>1)&7)  (16.6 KB)
__global__ __launch_bounds__(256, 2) void k_conv(const unsigned short* __restrict__ yt,
                                                 const unsigned short* __restrict__ wo,
                                                 const float* __restrict__ bo,
                                                 float* __restrict__ out) {
  __shared__ __align__(16) unsigned short As[128][128];
  __shared__ __align__(16) unsigned short Bs[130][64];
  int flat = blockIdx.x;                       // 1024 blocks
  int lg = ((flat & 7) << 7) + (flat >> 3);    // bijective XCD chunking
  int n_t = lg >> 1, m_t = lg & 1;
  int n0 = n_t << 8, m0 = m_t << 7;            // 256 p2 (one image row) x 128 o
  int tt = n0 >> 16, yy = (n0 >> 8) & 255;
  int tid = threadIdx.x;
  int w = tid >> 6, l = tid & 63;
  int wr = w >> 1, wc = w & 1;
  int l15 = l & 15, lhi = l >> 4;
  // staging roles
  int a_d0 = tid >> 7, a_o0 = tid & 127;       // A seg (d=0/1, o)
  bool doA1 = tid < 128;                        // A seg (d=2, o=tid)
  bool doBh = tid >= 254;                       // B halo xh=256,257 (xq=255,256)
  floatx4 zf = {0.f, 0.f, 0.f, 0.f};
  floatx4 acc[4][8];
#pragma unroll
  for (int i = 0; i < 4; ++i)
#pragma unroll
    for (int j = 0; j < 8; ++j) acc[i][j] = zf;
  uintx4 zu = {0u, 0u, 0u, 0u};
  uintx4 rb[4], ra0[4], ra1[4];
  const unsigned short* ybase = yt + (tt << 24);
#define CLOAD(ST) { \
    int dy = (ST) >> 3, cc = ((ST) & 7) << 5; \
    int yq = yy + dy - 1; \
    bool yv = (unsigned)yq < 256u; \
    { int xq = tid - 1; \
      if (yv && (unsigned)xq < 256u) { \
        const uintx4* p = (const uintx4*)(ybase + ((yq << 8) + xq) * 256 + cc); \
        rb[0] = p[0]; rb[1] = p[1]; rb[2] = p[2]; rb[3] = p[3]; \
      } else { rb[0] = zu; rb[1] = zu; rb[2] = zu; rb[3] = zu; } } \
    { const uintx4* p = (const uintx4*)(wo + (dy * 3 + a_d0) * 65536 + (m0 + a_o0) * 256 + cc); \
      ra0[0] = p[0]; ra0[1] = p[1]; ra0[2] = p[2]; ra0[3] = p[3]; } \
    if (doA1) { \
      const uintx4* p = (const uintx4*)(wo + (dy * 3 + 2) * 65536 + (m0 + tid) * 256 + cc); \
      ra1[0] = p[0]; ra1[1] = p[1]; ra1[2] = p[2]; ra1[3] = p[3]; \
    } else if (doBh) { \
      int xq = tid + 1;  /* 255, 256 */ \
      if (yv && xq < 256) { \
        const uintx4* p = (const uintx4*)(ybase + ((yq << 8) + xq) * 256 + cc); \
        ra1[0] = p[0]; ra1[1] = p[1]; ra1[2] = p[2]; ra1[3] = p[3]; \
      } else { ra1[0] = zu; ra1[1] = zu; ra1[2] = zu; ra1[3] = zu; } } }
  CLOAD(0);
  for (int st = 0; st < 24; ++st) {
    __syncthreads();
    {
      // B main: xh = tid (xq = tid-1)
      int brow = tid >> 1, bhf = (tid & 1) * 4, br7 = brow & 7;
#pragma unroll
      for (int j = 0; j < 4; ++j)
        *(uintx4*)&Bs[brow][((bhf + j) ^ br7) * 8] = rb[j];
      // A d0/d1
      int ao7 = a_o0 & 7;
#pragma unroll
      for (int j = 0; j < 4; ++j)
        *(uintx4*)&As[a_o0][((a_d0 * 4 + j) ^ ao7) * 8] = ra0[j];
      if (doA1) {
        int o7 = tid & 7;
#pragma unroll
        for (int j = 0; j < 4; ++j)
          *(uintx4*)&As[tid][((8 + j) ^ o7) * 8] = ra1[j];
      } else if (doBh) {
        int xh = tid + 2;  // 256, 257
        int brow2 = xh >> 1, bhf2 = (xh & 1) * 4, br72 = brow2 & 7;
#pragma unroll
        for (int j = 0; j < 4; ++j)
          *(uintx4*)&Bs[brow2][((bhf2 + j) ^ br72) * 8] = ra1[j];
      }
    }
    __syncthreads();
    if (st < 23) CLOAD(st + 1);
#pragma unroll
    for (int dx = 0; dx < 3; ++dx) {
      short8 af[4];
#pragma unroll
      for (int f = 0; f < 4; ++f) {
        int ol = wr * 64 + f * 16 + l15;
        af[f] = *(const short8*)&As[ol][((dx * 4 + lhi) ^ (ol & 7)) * 8];
      }
#pragma unroll
      for (int fn = 0; fn < 8; ++fn) {
        int xh = wc * 128 + fn * 16 + l15 + dx;
        short8 b = *(const short8*)&Bs[xh >> 1][((((xh & 1) * 4 + lhi)) ^ ((xh >> 1) & 7)) * 8];
#pragma unroll
        for (int fm = 0; fm < 4; ++fm)
          acc[fm][fn] = __builtin_amdgcn_mfma_f32_16x16x32_bf16(af[fm], b, acc[fm][fn], 0, 0, 0);
      }
    }
  }
#undef CLOAD
#pragma unroll
  for (int fm = 0; fm < 4; ++fm) {
    int o = m0 + wr * 64 + fm * 16 + lhi * 4;
#pragma unroll
    for (int rr = 0; rr < 4; ++rr) {
      float bias = bo[o + rr];
#pragma unroll
      for (int fn = 0; fn < 8; ++fn) {
        int xcol = wc * 128 + fn * 16 + l15;
        float z = acc[fm][fn][rr] + bias;
        out[((tt * 256 + o + rr) << 16) + (yy << 8) + xcol] = z > 0.f ? z : 0.2f * z;
      }
    }
  }
}

// ---------------------------------------------------------------------------
extern "C" void kernel_launch(void* const* d_in, const int* in_sizes, int n_in,
                              void* d_out, int out_size, void* d_ws, size_t ws_size,
                              hipStream_t stream) {
  const float* x   = (const float*)d_in[0];
  const float* m   = (const float*)d_in[1];
  const float* Wq  = (const float*)d_in[2];
  const float* bq  = (const float*)d_in[3];
  const float* Wk  = (const float*)d_in[4];
  const float* bk  = (const float*)d_in[5];
  const float* Wv  = (const float*)d_in[6];
  const float* bv  = (const float*)d_in[7];
  const float* Wmq = (const float*)d_in[8];
  const float* bmq = (const float*)d_in[9];
  const float* Wmk = (const float*)d_in[10];
  const float* bmk = (const float*)d_in[11];
  const float* Wo  = (const float*)d_in[12];
  const float* bo  = (const float*)d_in[13];

  char* ws = (char*)d_ws;
  unsigned short* qkv   = (unsigned short*)(ws);
  unsigned short* xt    = (unsigned short*)(ws + 201326592);
  unsigned short* wqkv  = (unsigned short*)(ws + 268435456);
  unsigned short* wobf  = (unsigned short*)(ws + 268828672);
  float* bias           = (float*)(ws + 270008320);
  float* msc            = (float*)(ws + 270011392);
  float* scores         = (float*)(ws + 270011456);
  float* G              = (float*)(ws + 271129920);
  float* rbuf           = (float*)(ws + 272248384);
  unsigned short* pbuf  = (unsigned short*)(ws + 272251104);
  float* out            = (float*)d_out;
  unsigned short* ynat  = (unsigned short*)d_out;  // low half of d_out as bf16 scratch
  unsigned short* yt    = xt;                      // reuse x_t space

  k_prep_w<<<dim3(769), dim3(256), 0, stream>>>(Wq, Wk, Wv, bq, bk, bv, Wmq, bmq, Wmk, bmk,
                                                wqkv, bias, msc);
  k_prep_wo<<<dim3(4489), dim3(256), 0, stream>>>(Wo, wobf, scores, (unsigned int*)pbuf);
  k_xt<<<dim3(1024, 4, 2), dim3(256), 0, stream>>>(x, xt);
  k_qkv<<<dim3(1024, 6), dim3(256), 0, stream>>>(xt, wqkv, bias, qkv);
  k_gram2<<<dim3(328), dim3(256), 0, stream>>>(m, G);
  k_rsum<<<dim3(680), dim3(64), 0, stream>>>(m, rbuf);
  k_scores2<<<dim3(1600), dim3(256), 0, stream>>>(qkv, scores);
  k_softmax<<<dim3(680), dim3(64), 0, stream>>>(scores, G, rbuf, msc, pbuf);
  k_pv<<<dim3(10240), dim3(256), 0, stream>>>(qkv, pbuf, ynat);
  k_yt<<<dim3(1024, 4, 2), dim3(256), 0, stream>>>(ynat, yt);
  k_conv<<<dim3(1024), dim3(256), 0, stream>>>(yt, wobf, bo, out);
}